// Round 17
// baseline (419.759 us; speedup 1.0000x reference)
//
#include <hip/hip_runtime.h>

#define NN 50000
#define NE 800000
#define D  128
#define NG 64
#define BN_EPS 1e-5f
#define SCAN_B 196   // ceil(NN/256)

typedef __attribute__((ext_vector_type(8))) short short8;
typedef __attribute__((ext_vector_type(4))) float f32x4;

static __device__ inline unsigned short f2bf_rn(float f) {
  unsigned u = __float_as_uint(f);
  unsigned r = (u + 0x7FFF + ((u >> 16) & 1)) >> 16;
  return (unsigned short)r;
}
static __device__ inline float bf2f(unsigned short h) {
  return __uint_as_float((unsigned)h << 16);
}

// ---------------- CSR build ----------------
__global__ void k_hist(const int* __restrict__ dst, int* __restrict__ counts) {
  int e = blockIdx.x * blockDim.x + threadIdx.x;
  if (e < NE) atomicAdd(&counts[dst[e]], 1);
}

__global__ void k_scan1(const int* __restrict__ counts, int* __restrict__ bsum) {
  const int t = threadIdx.x;
  const int i = blockIdx.x * 256 + t;
  int v = (i < NN) ? counts[i] : 0;
  #pragma unroll
  for (int d = 32; d >= 1; d >>= 1) v += __shfl_xor(v, d, 64);
  __shared__ int ws[4];
  if ((t & 63) == 0) ws[t >> 6] = v;
  __syncthreads();
  if (t == 0) bsum[blockIdx.x] = ws[0] + ws[1] + ws[2] + ws[3];
}

__global__ void k_scan2(const int* __restrict__ bsum, int* __restrict__ boff,
                        int* __restrict__ offs) {
  const int t = threadIdx.x, lane = t & 63, w = t >> 6;
  int v = (t < SCAN_B) ? bsum[t] : 0;
  int s = v;
  #pragma unroll
  for (int d = 1; d < 64; d <<= 1) { int u = __shfl_up(s, d, 64); if (lane >= d) s += u; }
  __shared__ int ws[4];
  if (lane == 63) ws[w] = s;
  __syncthreads();
  int add = 0;
  for (int k = 0; k < w; ++k) add += ws[k];
  if (t < SCAN_B) boff[t] = add + s - v;
  if (t == SCAN_B - 1) offs[NN] = add + s;
}

__global__ void k_scan3(const int* __restrict__ counts, const int* __restrict__ boff,
                        int* __restrict__ offs) {
  const int t = threadIdx.x, lane = t & 63, w = t >> 6;
  const int i = blockIdx.x * 256 + t;
  int v = (i < NN) ? counts[i] : 0;
  int s = v;
  #pragma unroll
  for (int d = 1; d < 64; d <<= 1) { int u = __shfl_up(s, d, 64); if (lane >= d) s += u; }
  __shared__ int ws[4];
  if (lane == 63) ws[w] = s;
  __syncthreads();
  int add = 0;
  for (int k = 0; k < w; ++k) add += ws[k];
  if (i < NN) offs[i] = boff[blockIdx.x] + add + s - v;
}

__global__ void k_scatter(const int* __restrict__ src, const int* __restrict__ dst,
                          const int* __restrict__ offs, int* __restrict__ cursor,
                          int* __restrict__ esrc) {
  int e = blockIdx.x * blockDim.x + threadIdx.x;
  if (e < NE) {
    int d = dst[e];
    int p = offs[d] + atomicAdd(&cursor[d], 1);
    esrc[p] = src[e];
  }
}

// ---------------- x fp32 -> bf16 (+ gbounds folded into last block) ----------------
__global__ __launch_bounds__(256) void k_cvt(const float* __restrict__ X,
                                             unsigned long long* __restrict__ Xb,
                                             const int* __restrict__ batch,
                                             int* __restrict__ gstart) {
  if (blockIdx.x == gridDim.x - 1) {
    const int g = threadIdx.x;
    if (g <= NG) {
      int lo = 0, hi = NN;
      while (lo < hi) { int mid = (lo + hi) >> 1; if (batch[mid] < g) lo = mid + 1; else hi = mid; }
      gstart[g] = lo;
    }
    return;
  }
  const int n4 = NN * D / 4;
  const int nb = gridDim.x - 1;
  for (int i = blockIdx.x * blockDim.x + threadIdx.x; i < n4; i += nb * blockDim.x) {
    float4 v = ((const float4*)X)[i];
    unsigned long long p = (unsigned long long)f2bf_rn(v.x) |
                           ((unsigned long long)f2bf_rn(v.y) << 16) |
                           ((unsigned long long)f2bf_rn(v.z) << 32) |
                           ((unsigned long long)f2bf_rn(v.w) << 48);
    Xb[i] = p;
  }
}

// ---------------- weight prep (all 6 weights in one launch) ----------------
struct WPtrs { const float* w[6]; };
__global__ void k_prep6(WPtrs ws, short* __restrict__ wb) {
  const int widx = blockIdx.y;
  const float* __restrict__ W = ws.w[widx];
  short* __restrict__ Wh = wb + (size_t)(widx * 2) * 16384;
  short* __restrict__ Wl = Wh + 16384;
  const int idx = blockIdx.x * 256 + threadIdx.x;   // 64 x 256 = 16384
  const int k = idx >> 7, c = idx & 127;
  const float v = W[idx];
  const unsigned short h = f2bf_rn(v);
  const unsigned short lo = f2bf_rn(v - bf2f(h));
  const int o = ((k >> 5) * 128 + c) * 32 + (k & 31);
  Wh[o] = (short)h;
  Wl[o] = (short)lo;
}

// ---------------- aggregation: 2 edges per wave (32 lanes x 8B each) ----------------
// Lane-half h (lane>>5) processes edges of parity h. Self term in half 0.
// Cross-half combine via shfl_xor(32). Also zeroes this layer's stats (block 0).
template<bool BN>
__global__ __launch_bounds__(256) void k_aggregate(const unsigned long long* __restrict__ Hb8,
                                                   const int* __restrict__ offs,
                                                   const int* __restrict__ esrc,
                                                   const float* __restrict__ sums,
                                                   const float* __restrict__ sumsq,
                                                   const float* __restrict__ gw,
                                                   const float* __restrict__ beta,
                                                   float* __restrict__ zstats,
                                                   unsigned long long* __restrict__ AGGh8,
                                                   unsigned long long* __restrict__ AGGl8) {
  if (blockIdx.x == 0 && threadIdx.x < 256) zstats[threadIdx.x] = 0.f;

  const int node = blockIdx.x * 4 + (threadIdx.x >> 6);
  const int lane = threadIdx.x & 63;
  const int sl = lane & 31, half = lane >> 5;     // lane covers cols sl*4 .. sl*4+3
  float4 sc = make_float4(1.f, 1.f, 1.f, 1.f), sh = make_float4(0.f, 0.f, 0.f, 0.f);
  if (BN) {
    const float4 s4 = ((const float4*)sums)[sl];
    const float4 q4 = ((const float4*)sumsq)[sl];
    const float4 g4 = ((const float4*)gw)[sl];
    const float4 b4 = ((const float4*)beta)[sl];
    const float mx = s4.x * (1.f / NN), my = s4.y * (1.f / NN);
    const float mz = s4.z * (1.f / NN), mw = s4.w * (1.f / NN);
    sc.x = g4.x / sqrtf(q4.x * (1.f / NN) - mx * mx + BN_EPS);
    sc.y = g4.y / sqrtf(q4.y * (1.f / NN) - my * my + BN_EPS);
    sc.z = g4.z / sqrtf(q4.z * (1.f / NN) - mz * mz + BN_EPS);
    sc.w = g4.w / sqrtf(q4.w * (1.f / NN) - mw * mw + BN_EPS);
    sh.x = b4.x - mx * sc.x;
    sh.y = b4.y - my * sc.y;
    sh.z = b4.z - mz * sc.z;
    sh.w = b4.w - mw * sc.w;
  }

  auto rd4 = [&](int r) -> float4 {
    const unsigned long long u = Hb8[(size_t)r * 32 + sl];
    float4 v = make_float4(bf2f((unsigned short)u),
                           bf2f((unsigned short)(u >> 16)),
                           bf2f((unsigned short)(u >> 32)),
                           bf2f((unsigned short)(u >> 48)));
    if (BN) {
      v.x = fmaxf(fmaf(v.x, sc.x, sh.x), 0.f);
      v.y = fmaxf(fmaf(v.y, sc.y, sh.y), 0.f);
      v.z = fmaxf(fmaf(v.z, sc.z, sh.z), 0.f);
      v.w = fmaxf(fmaf(v.w, sc.w, sh.w), 0.f);
    }
    return v;
  };

  float4 acc = make_float4(0.f, 0.f, 0.f, 0.f);
  if (half == 0) acc = rd4(node);
  const int b = offs[node], e = offs[node + 1];
  int i = b + half;
  // 8 edges per lane-half per iteration (16 rows in flight per wave)
  for (; i + 16 <= e; i += 16) {
    float4 v[8];
    #pragma unroll
    for (int q = 0; q < 8; ++q) v[q] = rd4(esrc[i + 2 * q]);
    float ax = 0.f, ay = 0.f, az = 0.f, aw = 0.f;
    #pragma unroll
    for (int q = 0; q < 8; ++q) { ax += v[q].x; ay += v[q].y; az += v[q].z; aw += v[q].w; }
    acc.x += ax; acc.y += ay; acc.z += az; acc.w += aw;
  }
  for (; i + 8 <= e; i += 8) {
    const float4 v0 = rd4(esrc[i]),     v1 = rd4(esrc[i + 2]);
    const float4 v2 = rd4(esrc[i + 4]), v3 = rd4(esrc[i + 6]);
    acc.x += (v0.x + v1.x) + (v2.x + v3.x);
    acc.y += (v0.y + v1.y) + (v2.y + v3.y);
    acc.z += (v0.z + v1.z) + (v2.z + v3.z);
    acc.w += (v0.w + v1.w) + (v2.w + v3.w);
  }
  for (; i < e; i += 2) {
    const float4 v = rd4(esrc[i]);
    acc.x += v.x; acc.y += v.y; acc.z += v.z; acc.w += v.w;
  }

  // combine halves
  acc.x += __shfl_xor(acc.x, 32, 64);
  acc.y += __shfl_xor(acc.y, 32, 64);
  acc.z += __shfl_xor(acc.z, 32, 64);
  acc.w += __shfl_xor(acc.w, 32, 64);

  if (half == 0) {
    const unsigned short h0 = f2bf_rn(acc.x), h1 = f2bf_rn(acc.y),
                         h2 = f2bf_rn(acc.z), h3 = f2bf_rn(acc.w);
    AGGh8[(size_t)node * 32 + sl] = (unsigned long long)h0 |
                                    ((unsigned long long)h1 << 16) |
                                    ((unsigned long long)h2 << 32) |
                                    ((unsigned long long)h3 << 48);
    const unsigned short l0 = f2bf_rn(acc.x - bf2f(h0)), l1 = f2bf_rn(acc.y - bf2f(h1)),
                         l2 = f2bf_rn(acc.z - bf2f(h2)), l3 = f2bf_rn(acc.w - bf2f(h3));
    AGGl8[(size_t)node * 32 + sl] = (unsigned long long)l0 |
                                    ((unsigned long long)l1 << 16) |
                                    ((unsigned long long)l2 << 32) |
                                    ((unsigned long long)l3 << 48);
  }
}

// ---------------- fused MLP: Hb = (relu(A@W1+b1))@W2+b2, both W's LDS-resident ----------------
// 512 threads = 8 waves, wave tile 32x64. LDS = 128 KB (regA: W1 then swizzled C1; regB: W2).
__global__ __launch_bounds__(512) void k_mlp2(const short* __restrict__ Ah,
                                              const short* __restrict__ Al,
                                              const short* __restrict__ W1h, const short* __restrict__ W1l,
                                              const short* __restrict__ W2h, const short* __restrict__ W2l,
                                              const float* __restrict__ b1, const float* __restrict__ b2,
                                              short* __restrict__ Hb,
                                              float* __restrict__ stats) {
  __shared__ __align__(16) short regA[32768];   // 64 KB: W1 hi|lo, then C1 hi|lo (swizzled)
  __shared__ __align__(16) short regB[32768];   // 64 KB: W2 hi|lo

  const int t = threadIdx.x;
  {
    const short8* __restrict__ g1h = (const short8*)W1h;
    const short8* __restrict__ g1l = (const short8*)W1l;
    const short8* __restrict__ g2h = (const short8*)W2h;
    const short8* __restrict__ g2l = (const short8*)W2l;
    short8* a8 = (short8*)regA;
    short8* b8 = (short8*)regB;
    #pragma unroll
    for (int i = 0; i < 4; ++i) {
      a8[i * 512 + t]        = g1h[i * 512 + t];
      a8[2048 + i * 512 + t] = g1l[i * 512 + t];
      b8[i * 512 + t]        = g2h[i * 512 + t];
      b8[2048 + i * 512 + t] = g2l[i * 512 + t];
    }
  }

  const int l = t & 63, w = t >> 6;
  const int lr = l & 15, fq = l >> 4, lk = fq * 8;
  const int rg = w & 3;           // row-group (32 rows each)
  const int cg = w >> 2;          // col-group (64 cols each)
  const int row0 = blockIdx.x * 128;

  short8 ah[2][4], al[2][4];
  {
    const short8 z = (short8)(0);
    #pragma unroll
    for (int rt = 0; rt < 2; ++rt) {
      const int arow = row0 + rg * 32 + rt * 16 + lr;
      const bool ok = arow < NN;
      #pragma unroll
      for (int kc = 0; kc < 4; ++kc) {
        ah[rt][kc] = ok ? *(const short8*)(Ah + (size_t)arow * D + kc * 32 + lk) : z;
        al[rt][kc] = ok ? *(const short8*)(Al + (size_t)arow * D + kc * 32 + lk) : z;
      }
    }
  }
  __syncthreads();

  // ---- GEMM1 ----
  f32x4 acc[2][4];
  #pragma unroll
  for (int rt = 0; rt < 2; ++rt)
    #pragma unroll
    for (int ct = 0; ct < 4; ++ct) acc[rt][ct] = (f32x4)(0.f);
  #pragma unroll
  for (int kc = 0; kc < 4; ++kc) {
    #pragma unroll
    for (int ct = 0; ct < 4; ++ct) {
      const int wc = cg * 64 + ct * 16 + lr;
      const short8 bh = *(const short8*)(&regA[(kc * 128 + wc) * 32 + lk]);
      const short8 bl = *(const short8*)(&regA[16384 + (kc * 128 + wc) * 32 + lk]);
      #pragma unroll
      for (int rt = 0; rt < 2; ++rt) {
        acc[rt][ct] = __builtin_amdgcn_mfma_f32_16x16x32_bf16(ah[rt][kc], bh, acc[rt][ct], 0, 0, 0);
        acc[rt][ct] = __builtin_amdgcn_mfma_f32_16x16x32_bf16(al[rt][kc], bh, acc[rt][ct], 0, 0, 0);
        acc[rt][ct] = __builtin_amdgcn_mfma_f32_16x16x32_bf16(ah[rt][kc], bl, acc[rt][ct], 0, 0, 0);
      }
    }
  }
  __syncthreads();

  // ---- C1 = relu(acc+b1) -> hi/lo bf16 into regA, stride 128, XOR-swizzled ----
  #pragma unroll
  for (int rt = 0; rt < 2; ++rt) {
    #pragma unroll
    for (int ct = 0; ct < 4; ++ct) {
      const int c = cg * 64 + ct * 16 + lr;
      const float bb = b1[c];
      #pragma unroll
      for (int j = 0; j < 4; ++j) {
        const int r = rg * 32 + rt * 16 + fq * 4 + j;
        const int swc = c ^ ((r & 7) << 3);
        const float v = fmaxf(acc[rt][ct][j] + bb, 0.f);
        const unsigned short h = f2bf_rn(v);
        regA[r * 128 + swc] = (short)h;
        regA[16384 + r * 128 + swc] = (short)f2bf_rn(v - bf2f(h));
      }
    }
  }
  __syncthreads();

  // ---- GEMM2 ----
  f32x4 acc2[2][4];
  #pragma unroll
  for (int rt = 0; rt < 2; ++rt)
    #pragma unroll
    for (int ct = 0; ct < 4; ++ct) acc2[rt][ct] = (f32x4)(0.f);
  #pragma unroll
  for (int kc = 0; kc < 4; ++kc) {
    short8 ch[2], cl[2];
    #pragma unroll
    for (int rt = 0; rt < 2; ++rt) {
      const int r = rg * 32 + rt * 16 + lr;
      const int swb = r * 128 + ((kc * 32 + lk) ^ ((r & 7) << 3));
      ch[rt] = *(const short8*)(regA + swb);
      cl[rt] = *(const short8*)(regA + 16384 + swb);
    }
    #pragma unroll
    for (int ct = 0; ct < 4; ++ct) {
      const int wc = cg * 64 + ct * 16 + lr;
      const short8 bh = *(const short8*)(&regB[(kc * 128 + wc) * 32 + lk]);
      const short8 bl = *(const short8*)(&regB[16384 + (kc * 128 + wc) * 32 + lk]);
      #pragma unroll
      for (int rt = 0; rt < 2; ++rt) {
        acc2[rt][ct] = __builtin_amdgcn_mfma_f32_16x16x32_bf16(ch[rt], bh, acc2[rt][ct], 0, 0, 0);
        acc2[rt][ct] = __builtin_amdgcn_mfma_f32_16x16x32_bf16(cl[rt], bh, acc2[rt][ct], 0, 0, 0);
        acc2[rt][ct] = __builtin_amdgcn_mfma_f32_16x16x32_bf16(ch[rt], bl, acc2[rt][ct], 0, 0, 0);
      }
    }
  }

  // ---- epilogue: +b2, bf16 Hb store, BN stats ----
  float ps[4], pq[4];
  #pragma unroll
  for (int ct = 0; ct < 4; ++ct) { ps[ct] = 0.f; pq[ct] = 0.f; }
  #pragma unroll
  for (int rt = 0; rt < 2; ++rt) {
    #pragma unroll
    for (int ct = 0; ct < 4; ++ct) {
      const int c = cg * 64 + ct * 16 + lr;
      const float bb = b2[c];
      #pragma unroll
      for (int j = 0; j < 4; ++j) {
        const int gr = row0 + rg * 32 + rt * 16 + fq * 4 + j;
        if (gr < NN) {
          const float v = acc2[rt][ct][j] + bb;
          Hb[(size_t)gr * D + c] = (short)f2bf_rn(v);
          ps[ct] += v; pq[ct] += v * v;
        }
      }
    }
  }
  __syncthreads();
  float* red  = (float*)regA;            // [16][132] padded
  float* redq = red + 16 * 132;
  const int grp = rg * 4 + fq;
  #pragma unroll
  for (int ct = 0; ct < 4; ++ct) {
    const int c = cg * 64 + ct * 16 + lr;
    red [grp * 132 + c] = ps[ct];
    redq[grp * 132 + c] = pq[ct];
  }
  __syncthreads();
  if (t < 128) {
    float s = 0.f, q = 0.f;
    #pragma unroll
    for (int g2 = 0; g2 < 16; ++g2) { s += red[g2 * 132 + t]; q += redq[g2 * 132 + t]; }
    atomicAdd(&stats[t], s);
    atomicAdd(&stats[128 + t], q);
  }
}

// ---------------- pooling ----------------
__global__ __launch_bounds__(256) void k_pool(const unsigned short* __restrict__ Hb,
                                              const float* __restrict__ sums,
                                              const float* __restrict__ sumsq,
                                              const float* __restrict__ gw,
                                              const float* __restrict__ beta,
                                              const int* __restrict__ gstart,
                                              float* __restrict__ pooled, int lofs) {
  const int g = blockIdx.y;
  const int s = gstart[g], e = gstart[g + 1];
  const int t = threadIdx.x, c = t & 127, half = t >> 7;
  const float m  = sums[c] * (1.f / NN);
  const float sc = gw[c] / sqrtf(sumsq[c] * (1.f / NN) - m * m + BN_EPS);
  const float sh = beta[c] - m * sc;
  const int len = e - s;
  const int nchunk = (int)gridDim.x;
  const int per = (len + nchunk - 1) / nchunk;
  const int r0 = s + (int)blockIdx.x * per;
  const int r1 = min(e, r0 + per);
  float sum = 0.f;
  for (int r = r0 + half; r < r1; r += 2)
    sum += fmaxf(fmaf(bf2f(Hb[r * D + c]), sc, sh), 0.f);
  __shared__ float red[256];
  red[t] = sum;
  __syncthreads();
  if (t < 128) atomicAdd(&pooled[g * 384 + lofs + c], red[t] + red[t + 128]);
}

// ---------------- prediction head ----------------
__global__ __launch_bounds__(128) void k_fc1(const float* __restrict__ pooled,
                                             const int* __restrict__ gstart,
                                             const float* __restrict__ W1,
                                             const float* __restrict__ b1,
                                             float* __restrict__ z1) {
  const int g = blockIdx.x, j = threadIdx.x;
  __shared__ float p[384];
  const float cnt = (float)(gstart[g + 1] - gstart[g]);
  const float inv = 1.f / fmaxf(cnt, 1.f);
  for (int k = j; k < 384; k += 128) p[k] = pooled[g * 384 + k] * inv;
  __syncthreads();
  float acc = b1[j];
  #pragma unroll 8
  for (int k = 0; k < 384; ++k) acc = fmaf(p[k], W1[k * 128 + j], acc);
  z1[g * 128 + j] = fmaxf(acc, 0.f);
}

__global__ __launch_bounds__(128) void k_head(const float* __restrict__ z1,
                                              const float* __restrict__ g,
                                              const float* __restrict__ beta,
                                              const float* __restrict__ W2,
                                              const float* __restrict__ b2,
                                              float* __restrict__ out) {
  __shared__ float z2[NG][129];
  __shared__ float w2s[128];
  const int j = threadIdx.x;
  w2s[j] = W2[j];
  float vals[NG];
  float s = 0.f, q = 0.f;
  for (int gg = 0; gg < NG; ++gg) {
    float v = z1[gg * 128 + j];
    vals[gg] = v; s += v; q += v * v;
  }
  const float m   = s / (float)NG;
  const float var = q / (float)NG - m * m;
  const float sc  = g[j] / sqrtf(var + BN_EPS);
  const float sh  = beta[j] - m * sc;
  for (int gg = 0; gg < NG; ++gg) z2[gg][j] = vals[gg] * sc + sh;
  __syncthreads();
  if (j < NG) {
    float acc = b2[0];
    #pragma unroll 8
    for (int k = 0; k < 128; ++k) acc += z2[j][k] * w2s[k];
    out[j] = acc;
  }
}

// ---------------- launch ----------------
extern "C" void kernel_launch(void* const* d_in, const int* in_sizes, int n_in,
                              void* d_out, int out_size, void* d_ws, size_t ws_size,
                              hipStream_t stream) {
  const float* x     = (const float*)d_in[0];
  const int*   e_src = (const int*)d_in[1];
  const int*   e_dst = e_src + NE;
  const int*   batch = (const int*)d_in[2];
  const float *lW1[3], *lb1[3], *lW2[3], *lb2[3], *lg[3], *lbeta[3];
  for (int l = 0; l < 3; ++l) {
    lW1[l]   = (const float*)d_in[3 + 6 * l + 0];
    lb1[l]   = (const float*)d_in[3 + 6 * l + 1];
    lW2[l]   = (const float*)d_in[3 + 6 * l + 2];
    lb2[l]   = (const float*)d_in[3 + 6 * l + 3];
    lg[l]    = (const float*)d_in[3 + 6 * l + 4];
    lbeta[l] = (const float*)d_in[3 + 6 * l + 5];
  }
  const float* pW1   = (const float*)d_in[21];
  const float* pb1   = (const float*)d_in[22];
  const float* pg    = (const float*)d_in[23];
  const float* pbeta = (const float*)d_in[24];
  const float* pW2   = (const float*)d_in[25];
  const float* pb2   = (const float*)d_in[26];
  float* out = (float*)d_out;

  char* w = (char*)d_ws;
  auto alloc = [&](size_t bytes) { char* p = w; w += (bytes + 255) & ~(size_t)255; return p; };
  short* AGGh   = (short*)alloc((size_t)NN * D * 2);
  short* AGGl   = (short*)alloc((size_t)NN * D * 2);
  short* Hb0    = (short*)alloc((size_t)NN * D * 2);
  short* Hb1    = (short*)alloc((size_t)NN * D * 2);
  short* xb     = Hb1;   // alias: xb dead before Hb1 is first written (layer-1 mlp2)
  int*   counts = (int*)alloc((size_t)NN * 4);
  int*   cursor = (int*)alloc((size_t)NN * 4);
  int*   offs   = (int*)alloc((size_t)(NN + 1) * 4);
  int*   esrc   = (int*)alloc((size_t)NE * 4);
  int*   bsum   = (int*)alloc((size_t)SCAN_B * 4);
  int*   boff   = (int*)alloc((size_t)SCAN_B * 4);
  int*   gstart = (int*)alloc((size_t)(NG + 1) * 4);
  float* stats  = (float*)alloc((size_t)3 * 256 * 4);   // per-layer sums[128]+sumsq[128]
  float* pooled = (float*)alloc((size_t)NG * 384 * 4);
  float* z1     = (float*)alloc((size_t)NG * 128 * 4);
  short* wb     = (short*)alloc((size_t)12 * 32768);    // 12 planes x 16384 shorts
  auto st = [&](int l) { return stats + (size_t)l * 256; };

  hipMemsetAsync(counts, 0, (size_t)NN * 4, stream);
  hipMemsetAsync(cursor, 0, (size_t)NN * 4, stream);
  hipMemsetAsync(pooled, 0, (size_t)NG * 384 * 4, stream);

  k_hist   <<<(NE + 255) / 256, 256, 0, stream>>>(e_dst, counts);
  k_scan1  <<<SCAN_B, 256, 0, stream>>>(counts, bsum);
  k_scan2  <<<1, 256, 0, stream>>>(bsum, boff, offs);
  k_scan3  <<<SCAN_B, 256, 0, stream>>>(counts, boff, offs);
  k_scatter<<<(NE + 255) / 256, 256, 0, stream>>>(e_src, e_dst, offs, cursor, esrc);
  k_cvt    <<<1025, 256, 0, stream>>>(x, (unsigned long long*)xb, batch, gstart);

  WPtrs ws;
  ws.w[0] = lW1[0]; ws.w[1] = lW2[0];
  ws.w[2] = lW1[1]; ws.w[3] = lW2[1];
  ws.w[4] = lW1[2]; ws.w[5] = lW2[2];
  k_prep6<<<dim3(64, 6), 256, 0, stream>>>(ws, wb);
  auto plane = [&](int widx, int hilo) { return wb + (size_t)(widx * 2 + hilo) * 16384; };

  short* Hbuf[2] = {Hb0, Hb1};
  const int mlp_grid = (NN + 127) / 128;
  for (int l = 0; l < 3; ++l) {
    if (l == 0)
      k_aggregate<false><<<NN / 4, 256, 0, stream>>>((const unsigned long long*)xb, offs, esrc,
                                                     nullptr, nullptr, nullptr, nullptr,
                                                     st(0), (unsigned long long*)AGGh,
                                                     (unsigned long long*)AGGl);
    else
      k_aggregate<true><<<NN / 4, 256, 0, stream>>>((const unsigned long long*)Hbuf[(l - 1) & 1],
                                                    offs, esrc,
                                                    st(l - 1), st(l - 1) + 128, lg[l - 1], lbeta[l - 1],
                                                    st(l), (unsigned long long*)AGGh,
                                                    (unsigned long long*)AGGl);
    k_mlp2<<<mlp_grid, 512, 0, stream>>>(AGGh, AGGl,
                                         plane(2 * l, 0), plane(2 * l, 1),
                                         plane(2 * l + 1, 0), plane(2 * l + 1, 1),
                                         lb1[l], lb2[l], Hbuf[l & 1], st(l));
    k_pool <<<dim3(8, NG), 256, 0, stream>>>((const unsigned short*)Hbuf[l & 1],
                                             st(l), st(l) + 128, lg[l], lbeta[l],
                                             gstart, pooled, l * 128);
  }

  k_fc1 <<<NG, 128, 0, stream>>>(pooled, gstart, pW1, pb1, z1);
  k_head<<<1, 128, 0, stream>>>(z1, pg, pbeta, pW2, pb2, out);
}

// Round 18
// 385.279 us; speedup vs baseline: 1.0895x; 1.0895x over previous
//
#include <hip/hip_runtime.h>

#define NN 50000
#define NE 800000
#define D  128
#define NG 64
#define BN_EPS 1e-5f
#define SCAN_B 196   // ceil(NN/256)

typedef __attribute__((ext_vector_type(8))) short short8;
typedef __attribute__((ext_vector_type(4))) float f32x4;

static __device__ inline unsigned short f2bf_rn(float f) {
  unsigned u = __float_as_uint(f);
  unsigned r = (u + 0x7FFF + ((u >> 16) & 1)) >> 16;
  return (unsigned short)r;
}
static __device__ inline float bf2f(unsigned short h) {
  return __uint_as_float((unsigned)h << 16);
}

// ---------------- CSR build ----------------
__global__ void k_hist(const int* __restrict__ dst, int* __restrict__ counts) {
  int e = blockIdx.x * blockDim.x + threadIdx.x;
  if (e < NE) atomicAdd(&counts[dst[e]], 1);
}

__global__ void k_scan1(const int* __restrict__ counts, int* __restrict__ bsum) {
  const int t = threadIdx.x;
  const int i = blockIdx.x * 256 + t;
  int v = (i < NN) ? counts[i] : 0;
  #pragma unroll
  for (int d = 32; d >= 1; d >>= 1) v += __shfl_xor(v, d, 64);
  __shared__ int ws[4];
  if ((t & 63) == 0) ws[t >> 6] = v;
  __syncthreads();
  if (t == 0) bsum[blockIdx.x] = ws[0] + ws[1] + ws[2] + ws[3];
}

__global__ void k_scan2(const int* __restrict__ bsum, int* __restrict__ boff,
                        int* __restrict__ offs) {
  const int t = threadIdx.x, lane = t & 63, w = t >> 6;
  int v = (t < SCAN_B) ? bsum[t] : 0;
  int s = v;
  #pragma unroll
  for (int d = 1; d < 64; d <<= 1) { int u = __shfl_up(s, d, 64); if (lane >= d) s += u; }
  __shared__ int ws[4];
  if (lane == 63) ws[w] = s;
  __syncthreads();
  int add = 0;
  for (int k = 0; k < w; ++k) add += ws[k];
  if (t < SCAN_B) boff[t] = add + s - v;
  if (t == SCAN_B - 1) offs[NN] = add + s;
}

__global__ void k_scan3(const int* __restrict__ counts, const int* __restrict__ boff,
                        int* __restrict__ offs) {
  const int t = threadIdx.x, lane = t & 63, w = t >> 6;
  const int i = blockIdx.x * 256 + t;
  int v = (i < NN) ? counts[i] : 0;
  int s = v;
  #pragma unroll
  for (int d = 1; d < 64; d <<= 1) { int u = __shfl_up(s, d, 64); if (lane >= d) s += u; }
  __shared__ int ws[4];
  if (lane == 63) ws[w] = s;
  __syncthreads();
  int add = 0;
  for (int k = 0; k < w; ++k) add += ws[k];
  if (i < NN) offs[i] = boff[blockIdx.x] + add + s - v;
}

__global__ void k_scatter(const int* __restrict__ src, const int* __restrict__ dst,
                          const int* __restrict__ offs, int* __restrict__ cursor,
                          int* __restrict__ esrc) {
  int e = blockIdx.x * blockDim.x + threadIdx.x;
  if (e < NE) {
    int d = dst[e];
    int p = offs[d] + atomicAdd(&cursor[d], 1);
    esrc[p] = src[e];
  }
}

// ---------------- x fp32 -> bf16 (+ gbounds folded into last block) ----------------
__global__ __launch_bounds__(256) void k_cvt(const float* __restrict__ X,
                                             unsigned long long* __restrict__ Xb,
                                             const int* __restrict__ batch,
                                             int* __restrict__ gstart) {
  if (blockIdx.x == gridDim.x - 1) {
    const int g = threadIdx.x;
    if (g <= NG) {
      int lo = 0, hi = NN;
      while (lo < hi) { int mid = (lo + hi) >> 1; if (batch[mid] < g) lo = mid + 1; else hi = mid; }
      gstart[g] = lo;
    }
    return;
  }
  const int n4 = NN * D / 4;
  const int nb = gridDim.x - 1;
  for (int i = blockIdx.x * blockDim.x + threadIdx.x; i < n4; i += nb * blockDim.x) {
    float4 v = ((const float4*)X)[i];
    unsigned long long p = (unsigned long long)f2bf_rn(v.x) |
                           ((unsigned long long)f2bf_rn(v.y) << 16) |
                           ((unsigned long long)f2bf_rn(v.z) << 32) |
                           ((unsigned long long)f2bf_rn(v.w) << 48);
    Xb[i] = p;
  }
}

// ---------------- weight prep (all 6 weights in one launch) ----------------
struct WPtrs { const float* w[6]; };
__global__ void k_prep6(WPtrs ws, short* __restrict__ wb) {
  const int widx = blockIdx.y;
  const float* __restrict__ W = ws.w[widx];
  short* __restrict__ Wh = wb + (size_t)(widx * 2) * 16384;
  short* __restrict__ Wl = Wh + 16384;
  const int idx = blockIdx.x * 256 + threadIdx.x;   // 64 x 256 = 16384
  const int k = idx >> 7, c = idx & 127;
  const float v = W[idx];
  const unsigned short h = f2bf_rn(v);
  const unsigned short lo = f2bf_rn(v - bf2f(h));
  const int o = ((k >> 5) * 128 + c) * 32 + (k & 31);
  Wh[o] = (short)h;
  Wl[o] = (short)lo;
}

// ---------------- aggregation on bf16 rows -> hi/lo bf16 planes ----------------
// Also zeroes THIS layer's stats buffer (block 0).
template<bool BN>
__global__ __launch_bounds__(256) void k_aggregate(const unsigned* __restrict__ Hb,
                                                   const int* __restrict__ offs,
                                                   const int* __restrict__ esrc,
                                                   const float* __restrict__ sums,
                                                   const float* __restrict__ sumsq,
                                                   const float* __restrict__ gw,
                                                   const float* __restrict__ beta,
                                                   float* __restrict__ zstats,
                                                   unsigned* __restrict__ AGGh,
                                                   unsigned* __restrict__ AGGl) {
  if (blockIdx.x == 0 && threadIdx.x < 256) zstats[threadIdx.x] = 0.f;

  const int node = blockIdx.x * 4 + (threadIdx.x >> 6);
  const int lane = threadIdx.x & 63;
  float2 sc = make_float2(1.f, 1.f), sh = make_float2(0.f, 0.f);
  if (BN) {
    const float2 s2 = ((const float2*)sums)[lane];
    const float2 q2 = ((const float2*)sumsq)[lane];
    const float2 g2 = ((const float2*)gw)[lane];
    const float2 b2 = ((const float2*)beta)[lane];
    const float mx = s2.x * (1.f / NN), my = s2.y * (1.f / NN);
    sc.x = g2.x / sqrtf(q2.x * (1.f / NN) - mx * mx + BN_EPS);
    sc.y = g2.y / sqrtf(q2.y * (1.f / NN) - my * my + BN_EPS);
    sh.x = b2.x - mx * sc.x;
    sh.y = b2.y - my * sc.y;
  }

  auto rd = [&](int r) -> float2 {
    const unsigned u = Hb[r * 64 + lane];
    float2 v = make_float2(bf2f((unsigned short)u), bf2f((unsigned short)(u >> 16)));
    if (BN) {
      v.x = fmaxf(fmaf(v.x, sc.x, sh.x), 0.f);
      v.y = fmaxf(fmaf(v.y, sc.y, sh.y), 0.f);
    }
    return v;
  };

  float2 acc = rd(node);
  const int b = offs[node], e = offs[node + 1];
  int i = b;
  for (; i + 16 <= e; i += 16) {
    float2 v[16];
    #pragma unroll
    for (int q = 0; q < 16; ++q) v[q] = rd(esrc[i + q]);
    float sx = 0.f, sy = 0.f;
    #pragma unroll
    for (int q = 0; q < 16; ++q) { sx += v[q].x; sy += v[q].y; }
    acc.x += sx; acc.y += sy;
  }
  for (; i + 4 <= e; i += 4) {
    const int s0 = esrc[i], s1 = esrc[i + 1], s2 = esrc[i + 2], s3 = esrc[i + 3];
    const float2 v0 = rd(s0), v1 = rd(s1), v2 = rd(s2), v3 = rd(s3);
    acc.x += (v0.x + v1.x) + (v2.x + v3.x);
    acc.y += (v0.y + v1.y) + (v2.y + v3.y);
  }
  for (; i < e; ++i) {
    const float2 v = rd(esrc[i]);
    acc.x += v.x; acc.y += v.y;
  }
  const unsigned short hx = f2bf_rn(acc.x), hy = f2bf_rn(acc.y);
  AGGh[node * 64 + lane] = (unsigned)hx | ((unsigned)hy << 16);
  const unsigned short lx = f2bf_rn(acc.x - bf2f(hx)), ly = f2bf_rn(acc.y - bf2f(hy));
  AGGl[node * 64 + lane] = (unsigned)lx | ((unsigned)ly << 16);
}

// ---------------- fused MLP: Hb = (relu(A@W1+b1))@W2+b2, both W's LDS-resident ----------------
// 512 threads = 8 waves, wave tile 32x64. LDS = 128 KB (regA: W1 then swizzled C1; regB: W2).
__global__ __launch_bounds__(512) void k_mlp2(const short* __restrict__ Ah,
                                              const short* __restrict__ Al,
                                              const short* __restrict__ W1h, const short* __restrict__ W1l,
                                              const short* __restrict__ W2h, const short* __restrict__ W2l,
                                              const float* __restrict__ b1, const float* __restrict__ b2,
                                              short* __restrict__ Hb,
                                              float* __restrict__ stats) {
  __shared__ __align__(16) short regA[32768];   // 64 KB: W1 hi|lo, then C1 hi|lo (swizzled)
  __shared__ __align__(16) short regB[32768];   // 64 KB: W2 hi|lo

  const int t = threadIdx.x;
  {
    const short8* __restrict__ g1h = (const short8*)W1h;
    const short8* __restrict__ g1l = (const short8*)W1l;
    const short8* __restrict__ g2h = (const short8*)W2h;
    const short8* __restrict__ g2l = (const short8*)W2l;
    short8* a8 = (short8*)regA;
    short8* b8 = (short8*)regB;
    #pragma unroll
    for (int i = 0; i < 4; ++i) {
      a8[i * 512 + t]        = g1h[i * 512 + t];
      a8[2048 + i * 512 + t] = g1l[i * 512 + t];
      b8[i * 512 + t]        = g2h[i * 512 + t];
      b8[2048 + i * 512 + t] = g2l[i * 512 + t];
    }
  }

  const int l = t & 63, w = t >> 6;
  const int lr = l & 15, fq = l >> 4, lk = fq * 8;
  const int rg = w & 3;           // row-group (32 rows each)
  const int cg = w >> 2;          // col-group (64 cols each)
  const int row0 = blockIdx.x * 128;

  short8 ah[2][4], al[2][4];
  {
    const short8 z = (short8)(0);
    #pragma unroll
    for (int rt = 0; rt < 2; ++rt) {
      const int arow = row0 + rg * 32 + rt * 16 + lr;
      const bool ok = arow < NN;
      #pragma unroll
      for (int kc = 0; kc < 4; ++kc) {
        ah[rt][kc] = ok ? *(const short8*)(Ah + (size_t)arow * D + kc * 32 + lk) : z;
        al[rt][kc] = ok ? *(const short8*)(Al + (size_t)arow * D + kc * 32 + lk) : z;
      }
    }
  }
  __syncthreads();

  // ---- GEMM1 ----
  f32x4 acc[2][4];
  #pragma unroll
  for (int rt = 0; rt < 2; ++rt)
    #pragma unroll
    for (int ct = 0; ct < 4; ++ct) acc[rt][ct] = (f32x4)(0.f);
  #pragma unroll
  for (int kc = 0; kc < 4; ++kc) {
    #pragma unroll
    for (int ct = 0; ct < 4; ++ct) {
      const int wc = cg * 64 + ct * 16 + lr;
      const short8 bh = *(const short8*)(&regA[(kc * 128 + wc) * 32 + lk]);
      const short8 bl = *(const short8*)(&regA[16384 + (kc * 128 + wc) * 32 + lk]);
      #pragma unroll
      for (int rt = 0; rt < 2; ++rt) {
        acc[rt][ct] = __builtin_amdgcn_mfma_f32_16x16x32_bf16(ah[rt][kc], bh, acc[rt][ct], 0, 0, 0);
        acc[rt][ct] = __builtin_amdgcn_mfma_f32_16x16x32_bf16(al[rt][kc], bh, acc[rt][ct], 0, 0, 0);
        acc[rt][ct] = __builtin_amdgcn_mfma_f32_16x16x32_bf16(ah[rt][kc], bl, acc[rt][ct], 0, 0, 0);
      }
    }
  }
  __syncthreads();

  // ---- C1 = relu(acc+b1) -> hi/lo bf16 into regA, stride 128, XOR-swizzled ----
  #pragma unroll
  for (int rt = 0; rt < 2; ++rt) {
    #pragma unroll
    for (int ct = 0; ct < 4; ++ct) {
      const int c = cg * 64 + ct * 16 + lr;
      const float bb = b1[c];
      #pragma unroll
      for (int j = 0; j < 4; ++j) {
        const int r = rg * 32 + rt * 16 + fq * 4 + j;
        const int swc = c ^ ((r & 7) << 3);
        const float v = fmaxf(acc[rt][ct][j] + bb, 0.f);
        const unsigned short h = f2bf_rn(v);
        regA[r * 128 + swc] = (short)h;
        regA[16384 + r * 128 + swc] = (short)f2bf_rn(v - bf2f(h));
      }
    }
  }
  __syncthreads();

  // ---- GEMM2 ----
  f32x4 acc2[2][4];
  #pragma unroll
  for (int rt = 0; rt < 2; ++rt)
    #pragma unroll
    for (int ct = 0; ct < 4; ++ct) acc2[rt][ct] = (f32x4)(0.f);
  #pragma unroll
  for (int kc = 0; kc < 4; ++kc) {
    short8 ch[2], cl[2];
    #pragma unroll
    for (int rt = 0; rt < 2; ++rt) {
      const int r = rg * 32 + rt * 16 + lr;
      const int swb = r * 128 + ((kc * 32 + lk) ^ ((r & 7) << 3));
      ch[rt] = *(const short8*)(regA + swb);
      cl[rt] = *(const short8*)(regA + 16384 + swb);
    }
    #pragma unroll
    for (int ct = 0; ct < 4; ++ct) {
      const int wc = cg * 64 + ct * 16 + lr;
      const short8 bh = *(const short8*)(&regB[(kc * 128 + wc) * 32 + lk]);
      const short8 bl = *(const short8*)(&regB[16384 + (kc * 128 + wc) * 32 + lk]);
      #pragma unroll
      for (int rt = 0; rt < 2; ++rt) {
        acc2[rt][ct] = __builtin_amdgcn_mfma_f32_16x16x32_bf16(ch[rt], bh, acc2[rt][ct], 0, 0, 0);
        acc2[rt][ct] = __builtin_amdgcn_mfma_f32_16x16x32_bf16(cl[rt], bh, acc2[rt][ct], 0, 0, 0);
        acc2[rt][ct] = __builtin_amdgcn_mfma_f32_16x16x32_bf16(ch[rt], bl, acc2[rt][ct], 0, 0, 0);
      }
    }
  }

  // ---- epilogue: +b2, bf16 Hb store, BN stats ----
  float ps[4], pq[4];
  #pragma unroll
  for (int ct = 0; ct < 4; ++ct) { ps[ct] = 0.f; pq[ct] = 0.f; }
  #pragma unroll
  for (int rt = 0; rt < 2; ++rt) {
    #pragma unroll
    for (int ct = 0; ct < 4; ++ct) {
      const int c = cg * 64 + ct * 16 + lr;
      const float bb = b2[c];
      #pragma unroll
      for (int j = 0; j < 4; ++j) {
        const int gr = row0 + rg * 32 + rt * 16 + fq * 4 + j;
        if (gr < NN) {
          const float v = acc2[rt][ct][j] + bb;
          Hb[(size_t)gr * D + c] = (short)f2bf_rn(v);
          ps[ct] += v; pq[ct] += v * v;
        }
      }
    }
  }
  __syncthreads();
  float* red  = (float*)regA;            // [16][132] padded
  float* redq = red + 16 * 132;
  const int grp = rg * 4 + fq;
  #pragma unroll
  for (int ct = 0; ct < 4; ++ct) {
    const int c = cg * 64 + ct * 16 + lr;
    red [grp * 132 + c] = ps[ct];
    redq[grp * 132 + c] = pq[ct];
  }
  __syncthreads();
  if (t < 128) {
    float s = 0.f, q = 0.f;
    #pragma unroll
    for (int g2 = 0; g2 < 16; ++g2) { s += red[g2 * 132 + t]; q += redq[g2 * 132 + t]; }
    atomicAdd(&stats[t], s);
    atomicAdd(&stats[128 + t], q);
  }
}

// ---------------- pooling ----------------
__global__ __launch_bounds__(256) void k_pool(const unsigned short* __restrict__ Hb,
                                              const float* __restrict__ sums,
                                              const float* __restrict__ sumsq,
                                              const float* __restrict__ gw,
                                              const float* __restrict__ beta,
                                              const int* __restrict__ gstart,
                                              float* __restrict__ pooled, int lofs) {
  const int g = blockIdx.y;
  const int s = gstart[g], e = gstart[g + 1];
  const int t = threadIdx.x, c = t & 127, half = t >> 7;
  const float m  = sums[c] * (1.f / NN);
  const float sc = gw[c] / sqrtf(sumsq[c] * (1.f / NN) - m * m + BN_EPS);
  const float sh = beta[c] - m * sc;
  const int len = e - s;
  const int nchunk = (int)gridDim.x;
  const int per = (len + nchunk - 1) / nchunk;
  const int r0 = s + (int)blockIdx.x * per;
  const int r1 = min(e, r0 + per);
  float sum = 0.f;
  for (int r = r0 + half; r < r1; r += 2)
    sum += fmaxf(fmaf(bf2f(Hb[r * D + c]), sc, sh), 0.f);
  __shared__ float red[256];
  red[t] = sum;
  __syncthreads();
  if (t < 128) atomicAdd(&pooled[g * 384 + lofs + c], red[t] + red[t + 128]);
}

// ---------------- prediction head ----------------
__global__ __launch_bounds__(128) void k_fc1(const float* __restrict__ pooled,
                                             const int* __restrict__ gstart,
                                             const float* __restrict__ W1,
                                             const float* __restrict__ b1,
                                             float* __restrict__ z1) {
  const int g = blockIdx.x, j = threadIdx.x;
  __shared__ float p[384];
  const float cnt = (float)(gstart[g + 1] - gstart[g]);
  const float inv = 1.f / fmaxf(cnt, 1.f);
  for (int k = j; k < 384; k += 128) p[k] = pooled[g * 384 + k] * inv;
  __syncthreads();
  float acc = b1[j];
  #pragma unroll 8
  for (int k = 0; k < 384; ++k) acc = fmaf(p[k], W1[k * 128 + j], acc);
  z1[g * 128 + j] = fmaxf(acc, 0.f);
}

__global__ __launch_bounds__(128) void k_head(const float* __restrict__ z1,
                                              const float* __restrict__ g,
                                              const float* __restrict__ beta,
                                              const float* __restrict__ W2,
                                              const float* __restrict__ b2,
                                              float* __restrict__ out) {
  __shared__ float z2[NG][129];
  __shared__ float w2s[128];
  const int j = threadIdx.x;
  w2s[j] = W2[j];
  float vals[NG];
  float s = 0.f, q = 0.f;
  for (int gg = 0; gg < NG; ++gg) {
    float v = z1[gg * 128 + j];
    vals[gg] = v; s += v; q += v * v;
  }
  const float m   = s / (float)NG;
  const float var = q / (float)NG - m * m;
  const float sc  = g[j] / sqrtf(var + BN_EPS);
  const float sh  = beta[j] - m * sc;
  for (int gg = 0; gg < NG; ++gg) z2[gg][j] = vals[gg] * sc + sh;
  __syncthreads();
  if (j < NG) {
    float acc = b2[0];
    #pragma unroll 8
    for (int k = 0; k < 128; ++k) acc += z2[j][k] * w2s[k];
    out[j] = acc;
  }
}

// ---------------- launch ----------------
extern "C" void kernel_launch(void* const* d_in, const int* in_sizes, int n_in,
                              void* d_out, int out_size, void* d_ws, size_t ws_size,
                              hipStream_t stream) {
  const float* x     = (const float*)d_in[0];
  const int*   e_src = (const int*)d_in[1];
  const int*   e_dst = e_src + NE;
  const int*   batch = (const int*)d_in[2];
  const float *lW1[3], *lb1[3], *lW2[3], *lb2[3], *lg[3], *lbeta[3];
  for (int l = 0; l < 3; ++l) {
    lW1[l]   = (const float*)d_in[3 + 6 * l + 0];
    lb1[l]   = (const float*)d_in[3 + 6 * l + 1];
    lW2[l]   = (const float*)d_in[3 + 6 * l + 2];
    lb2[l]   = (const float*)d_in[3 + 6 * l + 3];
    lg[l]    = (const float*)d_in[3 + 6 * l + 4];
    lbeta[l] = (const float*)d_in[3 + 6 * l + 5];
  }
  const float* pW1   = (const float*)d_in[21];
  const float* pb1   = (const float*)d_in[22];
  const float* pg    = (const float*)d_in[23];
  const float* pbeta = (const float*)d_in[24];
  const float* pW2   = (const float*)d_in[25];
  const float* pb2   = (const float*)d_in[26];
  float* out = (float*)d_out;

  char* w = (char*)d_ws;
  auto alloc = [&](size_t bytes) { char* p = w; w += (bytes + 255) & ~(size_t)255; return p; };
  short* AGGh   = (short*)alloc((size_t)NN * D * 2);
  short* AGGl   = (short*)alloc((size_t)NN * D * 2);
  short* Hb0    = (short*)alloc((size_t)NN * D * 2);
  short* Hb1    = (short*)alloc((size_t)NN * D * 2);
  short* xb     = Hb1;   // alias: xb dead before Hb1 is first written (layer-1 mlp2)
  int*   counts = (int*)alloc((size_t)NN * 4);
  int*   cursor = (int*)alloc((size_t)NN * 4);
  int*   offs   = (int*)alloc((size_t)(NN + 1) * 4);
  int*   esrc   = (int*)alloc((size_t)NE * 4);
  int*   bsum   = (int*)alloc((size_t)SCAN_B * 4);
  int*   boff   = (int*)alloc((size_t)SCAN_B * 4);
  int*   gstart = (int*)alloc((size_t)(NG + 1) * 4);
  float* stats  = (float*)alloc((size_t)3 * 256 * 4);   // per-layer sums[128]+sumsq[128]
  float* pooled = (float*)alloc((size_t)NG * 384 * 4);
  float* z1     = (float*)alloc((size_t)NG * 128 * 4);
  short* wb     = (short*)alloc((size_t)12 * 32768);    // 12 planes x 16384 shorts
  auto st = [&](int l) { return stats + (size_t)l * 256; };

  hipMemsetAsync(counts, 0, (size_t)NN * 4, stream);
  hipMemsetAsync(cursor, 0, (size_t)NN * 4, stream);
  hipMemsetAsync(pooled, 0, (size_t)NG * 384 * 4, stream);

  k_hist   <<<(NE + 255) / 256, 256, 0, stream>>>(e_dst, counts);
  k_scan1  <<<SCAN_B, 256, 0, stream>>>(counts, bsum);
  k_scan2  <<<1, 256, 0, stream>>>(bsum, boff, offs);
  k_scan3  <<<SCAN_B, 256, 0, stream>>>(counts, boff, offs);
  k_scatter<<<(NE + 255) / 256, 256, 0, stream>>>(e_src, e_dst, offs, cursor, esrc);
  k_cvt    <<<1025, 256, 0, stream>>>(x, (unsigned long long*)xb, batch, gstart);

  WPtrs ws;
  ws.w[0] = lW1[0]; ws.w[1] = lW2[0];
  ws.w[2] = lW1[1]; ws.w[3] = lW2[1];
  ws.w[4] = lW1[2]; ws.w[5] = lW2[2];
  k_prep6<<<dim3(64, 6), 256, 0, stream>>>(ws, wb);
  auto plane = [&](int widx, int hilo) { return wb + (size_t)(widx * 2 + hilo) * 16384; };

  short* Hbuf[2] = {Hb0, Hb1};
  const int mlp_grid = (NN + 127) / 128;
  for (int l = 0; l < 3; ++l) {
    if (l == 0)
      k_aggregate<false><<<NN / 4, 256, 0, stream>>>((const unsigned*)xb, offs, esrc,
                                                     nullptr, nullptr, nullptr, nullptr,
                                                     st(0), (unsigned*)AGGh, (unsigned*)AGGl);
    else
      k_aggregate<true><<<NN / 4, 256, 0, stream>>>((const unsigned*)Hbuf[(l - 1) & 1], offs, esrc,
                                                    st(l - 1), st(l - 1) + 128, lg[l - 1], lbeta[l - 1],
                                                    st(l), (unsigned*)AGGh, (unsigned*)AGGl);
    k_mlp2<<<mlp_grid, 512, 0, stream>>>(AGGh, AGGl,
                                         plane(2 * l, 0), plane(2 * l, 1),
                                         plane(2 * l + 1, 0), plane(2 * l + 1, 1),
                                         lb1[l], lb2[l], Hbuf[l & 1], st(l));
    k_pool <<<dim3(8, NG), 256, 0, stream>>>((const unsigned short*)Hbuf[l & 1],
                                             st(l), st(l) + 128, lg[l], lbeta[l],
                                             gstart, pooled, l * 128);
  }

  k_fc1 <<<NG, 128, 0, stream>>>(pooled, gstart, pW1, pb1, z1);
  k_head<<<1, 128, 0, stream>>>(z1, pg, pbeta, pW2, pb2, out);
}

// Round 19
// 383.181 us; speedup vs baseline: 1.0955x; 1.0055x over previous
//
#include <hip/hip_runtime.h>

#define NN 50000
#define NE 800000
#define D  128
#define NG 64
#define BN_EPS 1e-5f
#define SCAN_B 196   // ceil(NN/256)

typedef __attribute__((ext_vector_type(8))) short short8;
typedef __attribute__((ext_vector_type(4))) float f32x4;

static __device__ inline unsigned short f2bf_rn(float f) {
  unsigned u = __float_as_uint(f);
  unsigned r = (u + 0x7FFF + ((u >> 16) & 1)) >> 16;
  return (unsigned short)r;
}
static __device__ inline float bf2f(unsigned short h) {
  return __uint_as_float((unsigned)h << 16);
}

// ---------------- CSR build ----------------
__global__ void k_hist(const int* __restrict__ dst, int* __restrict__ counts) {
  int e = blockIdx.x * blockDim.x + threadIdx.x;
  if (e < NE) atomicAdd(&counts[dst[e]], 1);
}

__global__ void k_scan1(const int* __restrict__ counts, int* __restrict__ bsum) {
  const int t = threadIdx.x;
  const int i = blockIdx.x * 256 + t;
  int v = (i < NN) ? counts[i] : 0;
  #pragma unroll
  for (int d = 32; d >= 1; d >>= 1) v += __shfl_xor(v, d, 64);
  __shared__ int ws[4];
  if ((t & 63) == 0) ws[t >> 6] = v;
  __syncthreads();
  if (t == 0) bsum[blockIdx.x] = ws[0] + ws[1] + ws[2] + ws[3];
}

__global__ void k_scan2(const int* __restrict__ bsum, int* __restrict__ boff,
                        int* __restrict__ offs) {
  const int t = threadIdx.x, lane = t & 63, w = t >> 6;
  int v = (t < SCAN_B) ? bsum[t] : 0;
  int s = v;
  #pragma unroll
  for (int d = 1; d < 64; d <<= 1) { int u = __shfl_up(s, d, 64); if (lane >= d) s += u; }
  __shared__ int ws[4];
  if (lane == 63) ws[w] = s;
  __syncthreads();
  int add = 0;
  for (int k = 0; k < w; ++k) add += ws[k];
  if (t < SCAN_B) boff[t] = add + s - v;
  if (t == SCAN_B - 1) offs[NN] = add + s;
}

__global__ void k_scan3(const int* __restrict__ counts, const int* __restrict__ boff,
                        int* __restrict__ offs) {
  const int t = threadIdx.x, lane = t & 63, w = t >> 6;
  const int i = blockIdx.x * 256 + t;
  int v = (i < NN) ? counts[i] : 0;
  int s = v;
  #pragma unroll
  for (int d = 1; d < 64; d <<= 1) { int u = __shfl_up(s, d, 64); if (lane >= d) s += u; }
  __shared__ int ws[4];
  if (lane == 63) ws[w] = s;
  __syncthreads();
  int add = 0;
  for (int k = 0; k < w; ++k) add += ws[k];
  if (i < NN) offs[i] = boff[blockIdx.x] + add + s - v;
}

// esrc stored as ushort (NN < 65536): halves the random-store line footprint.
__global__ void k_scatter(const int* __restrict__ src, const int* __restrict__ dst,
                          const int* __restrict__ offs, int* __restrict__ cursor,
                          unsigned short* __restrict__ esrc) {
  int e = blockIdx.x * blockDim.x + threadIdx.x;
  if (e < NE) {
    int d = dst[e];
    int p = offs[d] + atomicAdd(&cursor[d], 1);
    esrc[p] = (unsigned short)src[e];
  }
}

// ---------------- x fp32 -> bf16 (+ gbounds folded into last block) ----------------
__global__ __launch_bounds__(256) void k_cvt(const float* __restrict__ X,
                                             unsigned long long* __restrict__ Xb,
                                             const int* __restrict__ batch,
                                             int* __restrict__ gstart) {
  if (blockIdx.x == gridDim.x - 1) {
    const int g = threadIdx.x;
    if (g <= NG) {
      int lo = 0, hi = NN;
      while (lo < hi) { int mid = (lo + hi) >> 1; if (batch[mid] < g) lo = mid + 1; else hi = mid; }
      gstart[g] = lo;
    }
    return;
  }
  const int n4 = NN * D / 4;
  const int nb = gridDim.x - 1;
  for (int i = blockIdx.x * blockDim.x + threadIdx.x; i < n4; i += nb * blockDim.x) {
    float4 v = ((const float4*)X)[i];
    unsigned long long p = (unsigned long long)f2bf_rn(v.x) |
                           ((unsigned long long)f2bf_rn(v.y) << 16) |
                           ((unsigned long long)f2bf_rn(v.z) << 32) |
                           ((unsigned long long)f2bf_rn(v.w) << 48);
    Xb[i] = p;
  }
}

// ---------------- weight prep (all 6 weights in one launch) ----------------
struct WPtrs { const float* w[6]; };
__global__ void k_prep6(WPtrs ws, short* __restrict__ wb) {
  const int widx = blockIdx.y;
  const float* __restrict__ W = ws.w[widx];
  short* __restrict__ Wh = wb + (size_t)(widx * 2) * 16384;
  short* __restrict__ Wl = Wh + 16384;
  const int idx = blockIdx.x * 256 + threadIdx.x;   // 64 x 256 = 16384
  const int k = idx >> 7, c = idx & 127;
  const float v = W[idx];
  const unsigned short h = f2bf_rn(v);
  const unsigned short lo = f2bf_rn(v - bf2f(h));
  const int o = ((k >> 5) * 128 + c) * 32 + (k & 31);
  Wh[o] = (short)h;
  Wl[o] = (short)lo;
}

// ---------------- aggregation on bf16 rows -> hi/lo bf16 planes ----------------
// Also zeroes THIS layer's stats buffer (block 0).
template<bool BN>
__global__ __launch_bounds__(256) void k_aggregate(const unsigned* __restrict__ Hb,
                                                   const int* __restrict__ offs,
                                                   const unsigned short* __restrict__ esrc,
                                                   const float* __restrict__ sums,
                                                   const float* __restrict__ sumsq,
                                                   const float* __restrict__ gw,
                                                   const float* __restrict__ beta,
                                                   float* __restrict__ zstats,
                                                   unsigned* __restrict__ AGGh,
                                                   unsigned* __restrict__ AGGl) {
  if (blockIdx.x == 0 && threadIdx.x < 256) zstats[threadIdx.x] = 0.f;

  const int node = blockIdx.x * 4 + (threadIdx.x >> 6);
  const int lane = threadIdx.x & 63;
  float2 sc = make_float2(1.f, 1.f), sh = make_float2(0.f, 0.f);
  if (BN) {
    const float2 s2 = ((const float2*)sums)[lane];
    const float2 q2 = ((const float2*)sumsq)[lane];
    const float2 g2 = ((const float2*)gw)[lane];
    const float2 b2 = ((const float2*)beta)[lane];
    const float mx = s2.x * (1.f / NN), my = s2.y * (1.f / NN);
    sc.x = g2.x / sqrtf(q2.x * (1.f / NN) - mx * mx + BN_EPS);
    sc.y = g2.y / sqrtf(q2.y * (1.f / NN) - my * my + BN_EPS);
    sh.x = b2.x - mx * sc.x;
    sh.y = b2.y - my * sc.y;
  }

  auto rd = [&](int r) -> float2 {
    const unsigned u = Hb[r * 64 + lane];
    float2 v = make_float2(bf2f((unsigned short)u), bf2f((unsigned short)(u >> 16)));
    if (BN) {
      v.x = fmaxf(fmaf(v.x, sc.x, sh.x), 0.f);
      v.y = fmaxf(fmaf(v.y, sc.y, sh.y), 0.f);
    }
    return v;
  };

  float2 acc = rd(node);
  const int b = offs[node], e = offs[node + 1];
  int i = b;
  for (; i + 16 <= e; i += 16) {
    float2 v[16];
    #pragma unroll
    for (int q = 0; q < 16; ++q) v[q] = rd((int)esrc[i + q]);
    float sx = 0.f, sy = 0.f;
    #pragma unroll
    for (int q = 0; q < 16; ++q) { sx += v[q].x; sy += v[q].y; }
    acc.x += sx; acc.y += sy;
  }
  for (; i + 4 <= e; i += 4) {
    const int s0 = esrc[i], s1 = esrc[i + 1], s2 = esrc[i + 2], s3 = esrc[i + 3];
    const float2 v0 = rd(s0), v1 = rd(s1), v2 = rd(s2), v3 = rd(s3);
    acc.x += (v0.x + v1.x) + (v2.x + v3.x);
    acc.y += (v0.y + v1.y) + (v2.y + v3.y);
  }
  for (; i < e; ++i) {
    const float2 v = rd((int)esrc[i]);
    acc.x += v.x; acc.y += v.y;
  }
  const unsigned short hx = f2bf_rn(acc.x), hy = f2bf_rn(acc.y);
  AGGh[node * 64 + lane] = (unsigned)hx | ((unsigned)hy << 16);
  const unsigned short lx = f2bf_rn(acc.x - bf2f(hx)), ly = f2bf_rn(acc.y - bf2f(hy));
  AGGl[node * 64 + lane] = (unsigned)lx | ((unsigned)ly << 16);
}

// ---------------- fused MLP: Hb = (relu(A@W1+b1))@W2+b2, both W's LDS-resident ----------------
// 512 threads = 8 waves, wave tile 32x64. LDS = 128 KB (regA: W1 then swizzled C1; regB: W2).
__global__ __launch_bounds__(512) void k_mlp2(const short* __restrict__ Ah,
                                              const short* __restrict__ Al,
                                              const short* __restrict__ W1h, const short* __restrict__ W1l,
                                              const short* __restrict__ W2h, const short* __restrict__ W2l,
                                              const float* __restrict__ b1, const float* __restrict__ b2,
                                              short* __restrict__ Hb,
                                              float* __restrict__ stats) {
  __shared__ __align__(16) short regA[32768];   // 64 KB: W1 hi|lo, then C1 hi|lo (swizzled)
  __shared__ __align__(16) short regB[32768];   // 64 KB: W2 hi|lo

  const int t = threadIdx.x;
  {
    const short8* __restrict__ g1h = (const short8*)W1h;
    const short8* __restrict__ g1l = (const short8*)W1l;
    const short8* __restrict__ g2h = (const short8*)W2h;
    const short8* __restrict__ g2l = (const short8*)W2l;
    short8* a8 = (short8*)regA;
    short8* b8 = (short8*)regB;
    #pragma unroll
    for (int i = 0; i < 4; ++i) {
      a8[i * 512 + t]        = g1h[i * 512 + t];
      a8[2048 + i * 512 + t] = g1l[i * 512 + t];
      b8[i * 512 + t]        = g2h[i * 512 + t];
      b8[2048 + i * 512 + t] = g2l[i * 512 + t];
    }
  }

  const int l = t & 63, w = t >> 6;
  const int lr = l & 15, fq = l >> 4, lk = fq * 8;
  const int rg = w & 3;           // row-group (32 rows each)
  const int cg = w >> 2;          // col-group (64 cols each)
  const int row0 = blockIdx.x * 128;

  short8 ah[2][4], al[2][4];
  {
    const short8 z = (short8)(0);
    #pragma unroll
    for (int rt = 0; rt < 2; ++rt) {
      const int arow = row0 + rg * 32 + rt * 16 + lr;
      const bool ok = arow < NN;
      #pragma unroll
      for (int kc = 0; kc < 4; ++kc) {
        ah[rt][kc] = ok ? *(const short8*)(Ah + (size_t)arow * D + kc * 32 + lk) : z;
        al[rt][kc] = ok ? *(const short8*)(Al + (size_t)arow * D + kc * 32 + lk) : z;
      }
    }
  }
  __syncthreads();

  // ---- GEMM1 ----
  f32x4 acc[2][4];
  #pragma unroll
  for (int rt = 0; rt < 2; ++rt)
    #pragma unroll
    for (int ct = 0; ct < 4; ++ct) acc[rt][ct] = (f32x4)(0.f);
  #pragma unroll
  for (int kc = 0; kc < 4; ++kc) {
    #pragma unroll
    for (int ct = 0; ct < 4; ++ct) {
      const int wc = cg * 64 + ct * 16 + lr;
      const short8 bh = *(const short8*)(&regA[(kc * 128 + wc) * 32 + lk]);
      const short8 bl = *(const short8*)(&regA[16384 + (kc * 128 + wc) * 32 + lk]);
      #pragma unroll
      for (int rt = 0; rt < 2; ++rt) {
        acc[rt][ct] = __builtin_amdgcn_mfma_f32_16x16x32_bf16(ah[rt][kc], bh, acc[rt][ct], 0, 0, 0);
        acc[rt][ct] = __builtin_amdgcn_mfma_f32_16x16x32_bf16(al[rt][kc], bh, acc[rt][ct], 0, 0, 0);
        acc[rt][ct] = __builtin_amdgcn_mfma_f32_16x16x32_bf16(ah[rt][kc], bl, acc[rt][ct], 0, 0, 0);
      }
    }
  }
  __syncthreads();

  // ---- C1 = relu(acc+b1) -> hi/lo bf16 into regA, stride 128, XOR-swizzled ----
  #pragma unroll
  for (int rt = 0; rt < 2; ++rt) {
    #pragma unroll
    for (int ct = 0; ct < 4; ++ct) {
      const int c = cg * 64 + ct * 16 + lr;
      const float bb = b1[c];
      #pragma unroll
      for (int j = 0; j < 4; ++j) {
        const int r = rg * 32 + rt * 16 + fq * 4 + j;
        const int swc = c ^ ((r & 7) << 3);
        const float v = fmaxf(acc[rt][ct][j] + bb, 0.f);
        const unsigned short h = f2bf_rn(v);
        regA[r * 128 + swc] = (short)h;
        regA[16384 + r * 128 + swc] = (short)f2bf_rn(v - bf2f(h));
      }
    }
  }
  __syncthreads();

  // ---- GEMM2 ----
  f32x4 acc2[2][4];
  #pragma unroll
  for (int rt = 0; rt < 2; ++rt)
    #pragma unroll
    for (int ct = 0; ct < 4; ++ct) acc2[rt][ct] = (f32x4)(0.f);
  #pragma unroll
  for (int kc = 0; kc < 4; ++kc) {
    short8 ch[2], cl[2];
    #pragma unroll
    for (int rt = 0; rt < 2; ++rt) {
      const int r = rg * 32 + rt * 16 + lr;
      const int swb = r * 128 + ((kc * 32 + lk) ^ ((r & 7) << 3));
      ch[rt] = *(const short8*)(regA + swb);
      cl[rt] = *(const short8*)(regA + 16384 + swb);
    }
    #pragma unroll
    for (int ct = 0; ct < 4; ++ct) {
      const int wc = cg * 64 + ct * 16 + lr;
      const short8 bh = *(const short8*)(&regB[(kc * 128 + wc) * 32 + lk]);
      const short8 bl = *(const short8*)(&regB[16384 + (kc * 128 + wc) * 32 + lk]);
      #pragma unroll
      for (int rt = 0; rt < 2; ++rt) {
        acc2[rt][ct] = __builtin_amdgcn_mfma_f32_16x16x32_bf16(ch[rt], bh, acc2[rt][ct], 0, 0, 0);
        acc2[rt][ct] = __builtin_amdgcn_mfma_f32_16x16x32_bf16(cl[rt], bh, acc2[rt][ct], 0, 0, 0);
        acc2[rt][ct] = __builtin_amdgcn_mfma_f32_16x16x32_bf16(ch[rt], bl, acc2[rt][ct], 0, 0, 0);
      }
    }
  }

  // ---- epilogue: +b2, bf16 Hb store, BN stats ----
  float ps[4], pq[4];
  #pragma unroll
  for (int ct = 0; ct < 4; ++ct) { ps[ct] = 0.f; pq[ct] = 0.f; }
  #pragma unroll
  for (int rt = 0; rt < 2; ++rt) {
    #pragma unroll
    for (int ct = 0; ct < 4; ++ct) {
      const int c = cg * 64 + ct * 16 + lr;
      const float bb = b2[c];
      #pragma unroll
      for (int j = 0; j < 4; ++j) {
        const int gr = row0 + rg * 32 + rt * 16 + fq * 4 + j;
        if (gr < NN) {
          const float v = acc2[rt][ct][j] + bb;
          Hb[(size_t)gr * D + c] = (short)f2bf_rn(v);
          ps[ct] += v; pq[ct] += v * v;
        }
      }
    }
  }
  __syncthreads();
  float* red  = (float*)regA;            // [16][132] padded
  float* redq = red + 16 * 132;
  const int grp = rg * 4 + fq;
  #pragma unroll
  for (int ct = 0; ct < 4; ++ct) {
    const int c = cg * 64 + ct * 16 + lr;
    red [grp * 132 + c] = ps[ct];
    redq[grp * 132 + c] = pq[ct];
  }
  __syncthreads();
  if (t < 128) {
    float s = 0.f, q = 0.f;
    #pragma unroll
    for (int g2 = 0; g2 < 16; ++g2) { s += red[g2 * 132 + t]; q += redq[g2 * 132 + t]; }
    atomicAdd(&stats[t], s);
    atomicAdd(&stats[128 + t], q);
  }
}

// ---------------- pooling ----------------
__global__ __launch_bounds__(256) void k_pool(const unsigned short* __restrict__ Hb,
                                              const float* __restrict__ sums,
                                              const float* __restrict__ sumsq,
                                              const float* __restrict__ gw,
                                              const float* __restrict__ beta,
                                              const int* __restrict__ gstart,
                                              float* __restrict__ pooled, int lofs) {
  const int g = blockIdx.y;
  const int s = gstart[g], e = gstart[g + 1];
  const int t = threadIdx.x, c = t & 127, half = t >> 7;
  const float m  = sums[c] * (1.f / NN);
  const float sc = gw[c] / sqrtf(sumsq[c] * (1.f / NN) - m * m + BN_EPS);
  const float sh = beta[c] - m * sc;
  const int len = e - s;
  const int nchunk = (int)gridDim.x;
  const int per = (len + nchunk - 1) / nchunk;
  const int r0 = s + (int)blockIdx.x * per;
  const int r1 = min(e, r0 + per);
  float sum = 0.f;
  for (int r = r0 + half; r < r1; r += 2)
    sum += fmaxf(fmaf(bf2f(Hb[r * D + c]), sc, sh), 0.f);
  __shared__ float red[256];
  red[t] = sum;
  __syncthreads();
  if (t < 128) atomicAdd(&pooled[g * 384 + lofs + c], red[t] + red[t + 128]);
}

// ---------------- prediction head ----------------
__global__ __launch_bounds__(128) void k_fc1(const float* __restrict__ pooled,
                                             const int* __restrict__ gstart,
                                             const float* __restrict__ W1,
                                             const float* __restrict__ b1,
                                             float* __restrict__ z1) {
  const int g = blockIdx.x, j = threadIdx.x;
  __shared__ float p[384];
  const float cnt = (float)(gstart[g + 1] - gstart[g]);
  const float inv = 1.f / fmaxf(cnt, 1.f);
  for (int k = j; k < 384; k += 128) p[k] = pooled[g * 384 + k] * inv;
  __syncthreads();
  float acc = b1[j];
  #pragma unroll 8
  for (int k = 0; k < 384; ++k) acc = fmaf(p[k], W1[k * 128 + j], acc);
  z1[g * 128 + j] = fmaxf(acc, 0.f);
}

__global__ __launch_bounds__(128) void k_head(const float* __restrict__ z1,
                                              const float* __restrict__ g,
                                              const float* __restrict__ beta,
                                              const float* __restrict__ W2,
                                              const float* __restrict__ b2,
                                              float* __restrict__ out) {
  __shared__ float z2[NG][129];
  __shared__ float w2s[128];
  const int j = threadIdx.x;
  w2s[j] = W2[j];
  float vals[NG];
  float s = 0.f, q = 0.f;
  for (int gg = 0; gg < NG; ++gg) {
    float v = z1[gg * 128 + j];
    vals[gg] = v; s += v; q += v * v;
  }
  const float m   = s / (float)NG;
  const float var = q / (float)NG - m * m;
  const float sc  = g[j] / sqrtf(var + BN_EPS);
  const float sh  = beta[j] - m * sc;
  for (int gg = 0; gg < NG; ++gg) z2[gg][j] = vals[gg] * sc + sh;
  __syncthreads();
  if (j < NG) {
    float acc = b2[0];
    #pragma unroll 8
    for (int k = 0; k < 128; ++k) acc += z2[j][k] * w2s[k];
    out[j] = acc;
  }
}

// ---------------- launch ----------------
extern "C" void kernel_launch(void* const* d_in, const int* in_sizes, int n_in,
                              void* d_out, int out_size, void* d_ws, size_t ws_size,
                              hipStream_t stream) {
  const float* x     = (const float*)d_in[0];
  const int*   e_src = (const int*)d_in[1];
  const int*   e_dst = e_src + NE;
  const int*   batch = (const int*)d_in[2];
  const float *lW1[3], *lb1[3], *lW2[3], *lb2[3], *lg[3], *lbeta[3];
  for (int l = 0; l < 3; ++l) {
    lW1[l]   = (const float*)d_in[3 + 6 * l + 0];
    lb1[l]   = (const float*)d_in[3 + 6 * l + 1];
    lW2[l]   = (const float*)d_in[3 + 6 * l + 2];
    lb2[l]   = (const float*)d_in[3 + 6 * l + 3];
    lg[l]    = (const float*)d_in[3 + 6 * l + 4];
    lbeta[l] = (const float*)d_in[3 + 6 * l + 5];
  }
  const float* pW1   = (const float*)d_in[21];
  const float* pb1   = (const float*)d_in[22];
  const float* pg    = (const float*)d_in[23];
  const float* pbeta = (const float*)d_in[24];
  const float* pW2   = (const float*)d_in[25];
  const float* pb2   = (const float*)d_in[26];
  float* out = (float*)d_out;

  char* w = (char*)d_ws;
  auto alloc = [&](size_t bytes) { char* p = w; w += (bytes + 255) & ~(size_t)255; return p; };
  short* AGGh   = (short*)alloc((size_t)NN * D * 2);
  short* AGGl   = (short*)alloc((size_t)NN * D * 2);
  short* Hb0    = (short*)alloc((size_t)NN * D * 2);
  short* Hb1    = (short*)alloc((size_t)NN * D * 2);
  short* xb     = Hb1;   // alias: xb dead before Hb1 is first written (layer-1 mlp2)
  int*   counts = (int*)alloc((size_t)NN * 4);
  int*   cursor = (int*)alloc((size_t)NN * 4);
  int*   offs   = (int*)alloc((size_t)(NN + 1) * 4);
  unsigned short* esrc = (unsigned short*)alloc((size_t)NE * 2);
  int*   bsum   = (int*)alloc((size_t)SCAN_B * 4);
  int*   boff   = (int*)alloc((size_t)SCAN_B * 4);
  int*   gstart = (int*)alloc((size_t)(NG + 1) * 4);
  float* stats  = (float*)alloc((size_t)3 * 256 * 4);   // per-layer sums[128]+sumsq[128]
  float* pooled = (float*)alloc((size_t)NG * 384 * 4);
  float* z1     = (float*)alloc((size_t)NG * 128 * 4);
  short* wb     = (short*)alloc((size_t)12 * 32768);    // 12 planes x 16384 shorts
  auto st = [&](int l) { return stats + (size_t)l * 256; };

  hipMemsetAsync(counts, 0, (size_t)NN * 4, stream);
  hipMemsetAsync(cursor, 0, (size_t)NN * 4, stream);
  hipMemsetAsync(pooled, 0, (size_t)NG * 384 * 4, stream);

  k_hist   <<<(NE + 255) / 256, 256, 0, stream>>>(e_dst, counts);
  k_scan1  <<<SCAN_B, 256, 0, stream>>>(counts, bsum);
  k_scan2  <<<1, 256, 0, stream>>>(bsum, boff, offs);
  k_scan3  <<<SCAN_B, 256, 0, stream>>>(counts, boff, offs);
  k_scatter<<<(NE + 255) / 256, 256, 0, stream>>>(e_src, e_dst, offs, cursor, esrc);
  k_cvt    <<<1025, 256, 0, stream>>>(x, (unsigned long long*)xb, batch, gstart);

  WPtrs ws;
  ws.w[0] = lW1[0]; ws.w[1] = lW2[0];
  ws.w[2] = lW1[1]; ws.w[3] = lW2[1];
  ws.w[4] = lW1[2]; ws.w[5] = lW2[2];
  k_prep6<<<dim3(64, 6), 256, 0, stream>>>(ws, wb);
  auto plane = [&](int widx, int hilo) { return wb + (size_t)(widx * 2 + hilo) * 16384; };

  short* Hbuf[2] = {Hb0, Hb1};
  const int mlp_grid = (NN + 127) / 128;
  for (int l = 0; l < 3; ++l) {
    if (l == 0)
      k_aggregate<false><<<NN / 4, 256, 0, stream>>>((const unsigned*)xb, offs, esrc,
                                                     nullptr, nullptr, nullptr, nullptr,
                                                     st(0), (unsigned*)AGGh, (unsigned*)AGGl);
    else
      k_aggregate<true><<<NN / 4, 256, 0, stream>>>((const unsigned*)Hbuf[(l - 1) & 1], offs, esrc,
                                                    st(l - 1), st(l - 1) + 128, lg[l - 1], lbeta[l - 1],
                                                    st(l), (unsigned*)AGGh, (unsigned*)AGGl);
    k_mlp2<<<mlp_grid, 512, 0, stream>>>(AGGh, AGGl,
                                         plane(2 * l, 0), plane(2 * l, 1),
                                         plane(2 * l + 1, 0), plane(2 * l + 1, 1),
                                         lb1[l], lb2[l], Hbuf[l & 1], st(l));
    k_pool <<<dim3(8, NG), 256, 0, stream>>>((const unsigned short*)Hbuf[l & 1],
                                             st(l), st(l) + 128, lg[l], lbeta[l],
                                             gstart, pooled, l * 128);
  }

  k_fc1 <<<NG, 128, 0, stream>>>(pooled, gstart, pW1, pb1, z1);
  k_head<<<1, 128, 0, stream>>>(z1, pg, pbeta, pW2, pb2, out);
}

// Round 20
// 372.719 us; speedup vs baseline: 1.1262x; 1.0281x over previous
//
#include <hip/hip_runtime.h>

#define NN 50000
#define NE 800000
#define D  128
#define NG 64
#define BN_EPS 1e-5f
#define SCAN_B 196   // ceil(NN/256)

typedef __attribute__((ext_vector_type(8))) short short8;
typedef __attribute__((ext_vector_type(4))) float f32x4;

static __device__ inline unsigned short f2bf_rn(float f) {
  unsigned u = __float_as_uint(f);
  unsigned r = (u + 0x7FFF + ((u >> 16) & 1)) >> 16;
  return (unsigned short)r;
}
static __device__ inline float bf2f(unsigned short h) {
  return __uint_as_float((unsigned)h << 16);
}

// ---------------- CSR build ----------------
__global__ void k_hist(const int* __restrict__ dst, int* __restrict__ counts) {
  int e = blockIdx.x * blockDim.x + threadIdx.x;
  if (e < NE) atomicAdd(&counts[dst[e]], 1);
}

__global__ void k_scan1(const int* __restrict__ counts, int* __restrict__ bsum) {
  const int t = threadIdx.x;
  const int i = blockIdx.x * 256 + t;
  int v = (i < NN) ? counts[i] : 0;
  #pragma unroll
  for (int d = 32; d >= 1; d >>= 1) v += __shfl_xor(v, d, 64);
  __shared__ int ws[4];
  if ((t & 63) == 0) ws[t >> 6] = v;
  __syncthreads();
  if (t == 0) bsum[blockIdx.x] = ws[0] + ws[1] + ws[2] + ws[3];
}

__global__ void k_scan2(const int* __restrict__ bsum, int* __restrict__ boff,
                        int* __restrict__ offs) {
  const int t = threadIdx.x, lane = t & 63, w = t >> 6;
  int v = (t < SCAN_B) ? bsum[t] : 0;
  int s = v;
  #pragma unroll
  for (int d = 1; d < 64; d <<= 1) { int u = __shfl_up(s, d, 64); if (lane >= d) s += u; }
  __shared__ int ws[4];
  if (lane == 63) ws[w] = s;
  __syncthreads();
  int add = 0;
  for (int k = 0; k < w; ++k) add += ws[k];
  if (t < SCAN_B) boff[t] = add + s - v;
  if (t == SCAN_B - 1) offs[NN] = add + s;
}

__global__ void k_scan3(const int* __restrict__ counts, const int* __restrict__ boff,
                        int* __restrict__ offs) {
  const int t = threadIdx.x, lane = t & 63, w = t >> 6;
  const int i = blockIdx.x * 256 + t;
  int v = (i < NN) ? counts[i] : 0;
  int s = v;
  #pragma unroll
  for (int d = 1; d < 64; d <<= 1) { int u = __shfl_up(s, d, 64); if (lane >= d) s += u; }
  __shared__ int ws[4];
  if (lane == 63) ws[w] = s;
  __syncthreads();
  int add = 0;
  for (int k = 0; k < w; ++k) add += ws[k];
  if (i < NN) offs[i] = boff[blockIdx.x] + add + s - v;
}

// esrc stored as ushort (NN < 65536): halves the random-store line footprint.
__global__ void k_scatter(const int* __restrict__ src, const int* __restrict__ dst,
                          const int* __restrict__ offs, int* __restrict__ cursor,
                          unsigned short* __restrict__ esrc) {
  int e = blockIdx.x * blockDim.x + threadIdx.x;
  if (e < NE) {
    int d = dst[e];
    int p = offs[d] + atomicAdd(&cursor[d], 1);
    esrc[p] = (unsigned short)src[e];
  }
}

// ---------------- x fp32 -> bf16 (+ gbounds folded into last block) ----------------
__global__ __launch_bounds__(256) void k_cvt(const float* __restrict__ X,
                                             unsigned long long* __restrict__ Xb,
                                             const int* __restrict__ batch,
                                             int* __restrict__ gstart) {
  if (blockIdx.x == gridDim.x - 1) {
    const int g = threadIdx.x;
    if (g <= NG) {
      int lo = 0, hi = NN;
      while (lo < hi) { int mid = (lo + hi) >> 1; if (batch[mid] < g) lo = mid + 1; else hi = mid; }
      gstart[g] = lo;
    }
    return;
  }
  const int n4 = NN * D / 4;
  const int nb = gridDim.x - 1;
  for (int i = blockIdx.x * blockDim.x + threadIdx.x; i < n4; i += nb * blockDim.x) {
    float4 v = ((const float4*)X)[i];
    unsigned long long p = (unsigned long long)f2bf_rn(v.x) |
                           ((unsigned long long)f2bf_rn(v.y) << 16) |
                           ((unsigned long long)f2bf_rn(v.z) << 32) |
                           ((unsigned long long)f2bf_rn(v.w) << 48);
    Xb[i] = p;
  }
}

// ---------------- weight prep (all 6 weights in one launch) ----------------
struct WPtrs { const float* w[6]; };
__global__ void k_prep6(WPtrs ws, short* __restrict__ wb) {
  const int widx = blockIdx.y;
  const float* __restrict__ W = ws.w[widx];
  short* __restrict__ Wh = wb + (size_t)(widx * 2) * 16384;
  short* __restrict__ Wl = Wh + 16384;
  const int idx = blockIdx.x * 256 + threadIdx.x;   // 64 x 256 = 16384
  const int k = idx >> 7, c = idx & 127;
  const float v = W[idx];
  const unsigned short h = f2bf_rn(v);
  const unsigned short lo = f2bf_rn(v - bf2f(h));
  const int o = ((k >> 5) * 128 + c) * 32 + (k & 31);
  Wh[o] = (short)h;
  Wl[o] = (short)lo;
}

// ---------------- aggregation on bf16 rows -> hi/lo bf16 planes ----------------
// Also zeroes THIS layer's stats buffer (block 0).
template<bool BN>
__global__ __launch_bounds__(256) void k_aggregate(const unsigned* __restrict__ Hb,
                                                   const int* __restrict__ offs,
                                                   const unsigned short* __restrict__ esrc,
                                                   const float* __restrict__ sums,
                                                   const float* __restrict__ sumsq,
                                                   const float* __restrict__ gw,
                                                   const float* __restrict__ beta,
                                                   float* __restrict__ zstats,
                                                   unsigned* __restrict__ AGGh,
                                                   unsigned* __restrict__ AGGl) {
  if (blockIdx.x == 0 && threadIdx.x < 256) zstats[threadIdx.x] = 0.f;

  const int node = blockIdx.x * 4 + (threadIdx.x >> 6);
  const int lane = threadIdx.x & 63;
  float2 sc = make_float2(1.f, 1.f), sh = make_float2(0.f, 0.f);
  if (BN) {
    const float2 s2 = ((const float2*)sums)[lane];
    const float2 q2 = ((const float2*)sumsq)[lane];
    const float2 g2 = ((const float2*)gw)[lane];
    const float2 b2 = ((const float2*)beta)[lane];
    const float mx = s2.x * (1.f / NN), my = s2.y * (1.f / NN);
    sc.x = g2.x / sqrtf(q2.x * (1.f / NN) - mx * mx + BN_EPS);
    sc.y = g2.y / sqrtf(q2.y * (1.f / NN) - my * my + BN_EPS);
    sh.x = b2.x - mx * sc.x;
    sh.y = b2.y - my * sc.y;
  }

  auto rd = [&](int r) -> float2 {
    const unsigned u = Hb[r * 64 + lane];
    float2 v = make_float2(bf2f((unsigned short)u), bf2f((unsigned short)(u >> 16)));
    if (BN) {
      v.x = fmaxf(fmaf(v.x, sc.x, sh.x), 0.f);
      v.y = fmaxf(fmaf(v.y, sc.y, sh.y), 0.f);
    }
    return v;
  };

  float2 acc = rd(node);
  const int b = offs[node], e = offs[node + 1];
  int i = b;
  for (; i + 16 <= e; i += 16) {
    float2 v[16];
    #pragma unroll
    for (int q = 0; q < 16; ++q) v[q] = rd((int)esrc[i + q]);
    float sx = 0.f, sy = 0.f;
    #pragma unroll
    for (int q = 0; q < 16; ++q) { sx += v[q].x; sy += v[q].y; }
    acc.x += sx; acc.y += sy;
  }
  for (; i + 4 <= e; i += 4) {
    const int s0 = esrc[i], s1 = esrc[i + 1], s2 = esrc[i + 2], s3 = esrc[i + 3];
    const float2 v0 = rd(s0), v1 = rd(s1), v2 = rd(s2), v3 = rd(s3);
    acc.x += (v0.x + v1.x) + (v2.x + v3.x);
    acc.y += (v0.y + v1.y) + (v2.y + v3.y);
  }
  for (; i < e; ++i) {
    const float2 v = rd((int)esrc[i]);
    acc.x += v.x; acc.y += v.y;
  }
  const unsigned short hx = f2bf_rn(acc.x), hy = f2bf_rn(acc.y);
  AGGh[node * 64 + lane] = (unsigned)hx | ((unsigned)hy << 16);
  const unsigned short lx = f2bf_rn(acc.x - bf2f(hx)), ly = f2bf_rn(acc.y - bf2f(hy));
  AGGl[node * 64 + lane] = (unsigned)lx | ((unsigned)ly << 16);
}

// ---------------- fused MLP, persistent 2-tile blocks ----------------
// 196 blocks x 256 rows (2 tiles of 128). W1+W2 staged once; W1 re-staged (L2-hot)
// between tiles since the C1 tile overwrites regA. Stats reduced once per block.
__global__ __launch_bounds__(512) void k_mlp2(const short* __restrict__ Ah,
                                              const short* __restrict__ Al,
                                              const short* __restrict__ W1h, const short* __restrict__ W1l,
                                              const short* __restrict__ W2h, const short* __restrict__ W2l,
                                              const float* __restrict__ b1, const float* __restrict__ b2,
                                              short* __restrict__ Hb,
                                              float* __restrict__ stats) {
  __shared__ __align__(16) short regA[32768];   // 64 KB: W1 hi|lo <-> C1 hi|lo (swizzled)
  __shared__ __align__(16) short regB[32768];   // 64 KB: W2 hi|lo

  const int t = threadIdx.x;
  {
    const short8* __restrict__ g1h = (const short8*)W1h;
    const short8* __restrict__ g1l = (const short8*)W1l;
    const short8* __restrict__ g2h = (const short8*)W2h;
    const short8* __restrict__ g2l = (const short8*)W2l;
    short8* a8 = (short8*)regA;
    short8* b8 = (short8*)regB;
    #pragma unroll
    for (int i = 0; i < 4; ++i) {
      a8[i * 512 + t]        = g1h[i * 512 + t];
      a8[2048 + i * 512 + t] = g1l[i * 512 + t];
      b8[i * 512 + t]        = g2h[i * 512 + t];
      b8[2048 + i * 512 + t] = g2l[i * 512 + t];
    }
  }

  const int l = t & 63, w = t >> 6;
  const int lr = l & 15, fq = l >> 4, lk = fq * 8;
  const int rg = w & 3;           // row-group (32 rows each)
  const int cg = w >> 2;          // col-group (64 cols each)
  const int row_base = blockIdx.x * 256;

  float ps[4], pq[4];
  #pragma unroll
  for (int ct = 0; ct < 4; ++ct) { ps[ct] = 0.f; pq[ct] = 0.f; }

  auto tile = [&](int tile0) {
    // A fragments for this tile (overlaps whatever staging preceded)
    short8 ah[2][4], al[2][4];
    {
      const short8 z = (short8)(0);
      #pragma unroll
      for (int rt = 0; rt < 2; ++rt) {
        const int arow = tile0 + rg * 32 + rt * 16 + lr;
        const bool ok = arow < NN;
        #pragma unroll
        for (int kc = 0; kc < 4; ++kc) {
          ah[rt][kc] = ok ? *(const short8*)(Ah + (size_t)arow * D + kc * 32 + lk) : z;
          al[rt][kc] = ok ? *(const short8*)(Al + (size_t)arow * D + kc * 32 + lk) : z;
        }
      }
    }
    __syncthreads();   // W1 staging/restaging complete

    // ---- GEMM1 ----
    f32x4 acc[2][4];
    #pragma unroll
    for (int rt = 0; rt < 2; ++rt)
      #pragma unroll
      for (int ct = 0; ct < 4; ++ct) acc[rt][ct] = (f32x4)(0.f);
    #pragma unroll
    for (int kc = 0; kc < 4; ++kc) {
      #pragma unroll
      for (int ct = 0; ct < 4; ++ct) {
        const int wc = cg * 64 + ct * 16 + lr;
        const short8 bh = *(const short8*)(&regA[(kc * 128 + wc) * 32 + lk]);
        const short8 bl = *(const short8*)(&regA[16384 + (kc * 128 + wc) * 32 + lk]);
        #pragma unroll
        for (int rt = 0; rt < 2; ++rt) {
          acc[rt][ct] = __builtin_amdgcn_mfma_f32_16x16x32_bf16(ah[rt][kc], bh, acc[rt][ct], 0, 0, 0);
          acc[rt][ct] = __builtin_amdgcn_mfma_f32_16x16x32_bf16(al[rt][kc], bh, acc[rt][ct], 0, 0, 0);
          acc[rt][ct] = __builtin_amdgcn_mfma_f32_16x16x32_bf16(ah[rt][kc], bl, acc[rt][ct], 0, 0, 0);
        }
      }
    }
    __syncthreads();   // all W1 reads done; regA reusable

    // ---- C1 = relu(acc+b1) -> hi/lo bf16 into regA, stride 128, XOR-swizzled ----
    #pragma unroll
    for (int rt = 0; rt < 2; ++rt) {
      #pragma unroll
      for (int ct = 0; ct < 4; ++ct) {
        const int c = cg * 64 + ct * 16 + lr;
        const float bb = b1[c];
        #pragma unroll
        for (int j = 0; j < 4; ++j) {
          const int r = rg * 32 + rt * 16 + fq * 4 + j;
          const int swc = c ^ ((r & 7) << 3);
          const float v = fmaxf(acc[rt][ct][j] + bb, 0.f);
          const unsigned short h = f2bf_rn(v);
          regA[r * 128 + swc] = (short)h;
          regA[16384 + r * 128 + swc] = (short)f2bf_rn(v - bf2f(h));
        }
      }
    }
    __syncthreads();

    // ---- GEMM2 ----
    f32x4 acc2[2][4];
    #pragma unroll
    for (int rt = 0; rt < 2; ++rt)
      #pragma unroll
      for (int ct = 0; ct < 4; ++ct) acc2[rt][ct] = (f32x4)(0.f);
    #pragma unroll
    for (int kc = 0; kc < 4; ++kc) {
      short8 ch[2], cl[2];
      #pragma unroll
      for (int rt = 0; rt < 2; ++rt) {
        const int r = rg * 32 + rt * 16 + lr;
        const int swb = r * 128 + ((kc * 32 + lk) ^ ((r & 7) << 3));
        ch[rt] = *(const short8*)(regA + swb);
        cl[rt] = *(const short8*)(regA + 16384 + swb);
      }
      #pragma unroll
      for (int ct = 0; ct < 4; ++ct) {
        const int wc = cg * 64 + ct * 16 + lr;
        const short8 bh = *(const short8*)(&regB[(kc * 128 + wc) * 32 + lk]);
        const short8 bl = *(const short8*)(&regB[16384 + (kc * 128 + wc) * 32 + lk]);
        #pragma unroll
        for (int rt = 0; rt < 2; ++rt) {
          acc2[rt][ct] = __builtin_amdgcn_mfma_f32_16x16x32_bf16(ch[rt], bh, acc2[rt][ct], 0, 0, 0);
          acc2[rt][ct] = __builtin_amdgcn_mfma_f32_16x16x32_bf16(cl[rt], bh, acc2[rt][ct], 0, 0, 0);
          acc2[rt][ct] = __builtin_amdgcn_mfma_f32_16x16x32_bf16(ch[rt], bl, acc2[rt][ct], 0, 0, 0);
        }
      }
    }

    // ---- epilogue: +b2, bf16 Hb store, stats partials (accumulated across tiles) ----
    #pragma unroll
    for (int rt = 0; rt < 2; ++rt) {
      #pragma unroll
      for (int ct = 0; ct < 4; ++ct) {
        const int c = cg * 64 + ct * 16 + lr;
        const float bb = b2[c];
        #pragma unroll
        for (int j = 0; j < 4; ++j) {
          const int gr = tile0 + rg * 32 + rt * 16 + fq * 4 + j;
          if (gr < NN) {
            const float v = acc2[rt][ct][j] + bb;
            Hb[(size_t)gr * D + c] = (short)f2bf_rn(v);
            ps[ct] += v; pq[ct] += v * v;
          }
        }
      }
    }
  };

  tile(row_base);
  __syncthreads();   // all C1(tile0) reads done before regA overwrite
  {                  // restage W1 (L2-hot)
    const short8* __restrict__ g1h = (const short8*)W1h;
    const short8* __restrict__ g1l = (const short8*)W1l;
    short8* a8 = (short8*)regA;
    #pragma unroll
    for (int i = 0; i < 4; ++i) {
      a8[i * 512 + t]        = g1h[i * 512 + t];
      a8[2048 + i * 512 + t] = g1l[i * 512 + t];
    }
  }
  tile(row_base + 128);
  __syncthreads();   // all C1(tile1) reads done; regA reusable for reduction

  float* red  = (float*)regA;            // [16][132] padded
  float* redq = red + 16 * 132;
  const int grp = rg * 4 + fq;
  #pragma unroll
  for (int ct = 0; ct < 4; ++ct) {
    const int c = cg * 64 + ct * 16 + lr;
    red [grp * 132 + c] = ps[ct];
    redq[grp * 132 + c] = pq[ct];
  }
  __syncthreads();
  if (t < 128) {
    float s = 0.f, q = 0.f;
    #pragma unroll
    for (int g2 = 0; g2 < 16; ++g2) { s += red[g2 * 132 + t]; q += redq[g2 * 132 + t]; }
    atomicAdd(&stats[t], s);
    atomicAdd(&stats[128 + t], q);
  }
}

// ---------------- pooling ----------------
__global__ __launch_bounds__(256) void k_pool(const unsigned short* __restrict__ Hb,
                                              const float* __restrict__ sums,
                                              const float* __restrict__ sumsq,
                                              const float* __restrict__ gw,
                                              const float* __restrict__ beta,
                                              const int* __restrict__ gstart,
                                              float* __restrict__ pooled, int lofs) {
  const int g = blockIdx.y;
  const int s = gstart[g], e = gstart[g + 1];
  const int t = threadIdx.x, c = t & 127, half = t >> 7;
  const float m  = sums[c] * (1.f / NN);
  const float sc = gw[c] / sqrtf(sumsq[c] * (1.f / NN) - m * m + BN_EPS);
  const float sh = beta[c] - m * sc;
  const int len = e - s;
  const int nchunk = (int)gridDim.x;
  const int per = (len + nchunk - 1) / nchunk;
  const int r0 = s + (int)blockIdx.x * per;
  const int r1 = min(e, r0 + per);
  float sum = 0.f;
  for (int r = r0 + half; r < r1; r += 2)
    sum += fmaxf(fmaf(bf2f(Hb[r * D + c]), sc, sh), 0.f);
  __shared__ float red[256];
  red[t] = sum;
  __syncthreads();
  if (t < 128) atomicAdd(&pooled[g * 384 + lofs + c], red[t] + red[t + 128]);
}

// ---------------- prediction head ----------------
__global__ __launch_bounds__(128) void k_fc1(const float* __restrict__ pooled,
                                             const int* __restrict__ gstart,
                                             const float* __restrict__ W1,
                                             const float* __restrict__ b1,
                                             float* __restrict__ z1) {
  const int g = blockIdx.x, j = threadIdx.x;
  __shared__ float p[384];
  const float cnt = (float)(gstart[g + 1] - gstart[g]);
  const float inv = 1.f / fmaxf(cnt, 1.f);
  for (int k = j; k < 384; k += 128) p[k] = pooled[g * 384 + k] * inv;
  __syncthreads();
  float acc = b1[j];
  #pragma unroll 8
  for (int k = 0; k < 384; ++k) acc = fmaf(p[k], W1[k * 128 + j], acc);
  z1[g * 128 + j] = fmaxf(acc, 0.f);
}

__global__ __launch_bounds__(128) void k_head(const float* __restrict__ z1,
                                              const float* __restrict__ g,
                                              const float* __restrict__ beta,
                                              const float* __restrict__ W2,
                                              const float* __restrict__ b2,
                                              float* __restrict__ out) {
  __shared__ float z2[NG][129];
  __shared__ float w2s[128];
  const int j = threadIdx.x;
  w2s[j] = W2[j];
  float vals[NG];
  float s = 0.f, q = 0.f;
  for (int gg = 0; gg < NG; ++gg) {
    float v = z1[gg * 128 + j];
    vals[gg] = v; s += v; q += v * v;
  }
  const float m   = s / (float)NG;
  const float var = q / (float)NG - m * m;
  const float sc  = g[j] / sqrtf(var + BN_EPS);
  const float sh  = beta[j] - m * sc;
  for (int gg = 0; gg < NG; ++gg) z2[gg][j] = vals[gg] * sc + sh;
  __syncthreads();
  if (j < NG) {
    float acc = b2[0];
    #pragma unroll 8
    for (int k = 0; k < 128; ++k) acc += z2[j][k] * w2s[k];
    out[j] = acc;
  }
}

// ---------------- launch ----------------
extern "C" void kernel_launch(void* const* d_in, const int* in_sizes, int n_in,
                              void* d_out, int out_size, void* d_ws, size_t ws_size,
                              hipStream_t stream) {
  const float* x     = (const float*)d_in[0];
  const int*   e_src = (const int*)d_in[1];
  const int*   e_dst = e_src + NE;
  const int*   batch = (const int*)d_in[2];
  const float *lW1[3], *lb1[3], *lW2[3], *lb2[3], *lg[3], *lbeta[3];
  for (int l = 0; l < 3; ++l) {
    lW1[l]   = (const float*)d_in[3 + 6 * l + 0];
    lb1[l]   = (const float*)d_in[3 + 6 * l + 1];
    lW2[l]   = (const float*)d_in[3 + 6 * l + 2];
    lb2[l]   = (const float*)d_in[3 + 6 * l + 3];
    lg[l]    = (const float*)d_in[3 + 6 * l + 4];
    lbeta[l] = (const float*)d_in[3 + 6 * l + 5];
  }
  const float* pW1   = (const float*)d_in[21];
  const float* pb1   = (const float*)d_in[22];
  const float* pg    = (const float*)d_in[23];
  const float* pbeta = (const float*)d_in[24];
  const float* pW2   = (const float*)d_in[25];
  const float* pb2   = (const float*)d_in[26];
  float* out = (float*)d_out;

  char* w = (char*)d_ws;
  auto alloc = [&](size_t bytes) { char* p = w; w += (bytes + 255) & ~(size_t)255; return p; };
  short* AGGh   = (short*)alloc((size_t)NN * D * 2);
  short* AGGl   = (short*)alloc((size_t)NN * D * 2);
  short* Hb0    = (short*)alloc((size_t)NN * D * 2);
  short* Hb1    = (short*)alloc((size_t)NN * D * 2);
  short* xb     = Hb1;   // alias: xb dead before Hb1 is first written (layer-1 mlp2)
  int*   counts = (int*)alloc((size_t)NN * 4);
  int*   cursor = (int*)alloc((size_t)NN * 4);
  int*   offs   = (int*)alloc((size_t)(NN + 1) * 4);
  unsigned short* esrc = (unsigned short*)alloc((size_t)NE * 2);
  int*   bsum   = (int*)alloc((size_t)SCAN_B * 4);
  int*   boff   = (int*)alloc((size_t)SCAN_B * 4);
  int*   gstart = (int*)alloc((size_t)(NG + 1) * 4);
  float* stats  = (float*)alloc((size_t)3 * 256 * 4);   // per-layer sums[128]+sumsq[128]
  float* pooled = (float*)alloc((size_t)NG * 384 * 4);
  float* z1     = (float*)alloc((size_t)NG * 128 * 4);
  short* wb     = (short*)alloc((size_t)12 * 32768);    // 12 planes x 16384 shorts
  auto st = [&](int l) { return stats + (size_t)l * 256; };

  hipMemsetAsync(counts, 0, (size_t)NN * 4, stream);
  hipMemsetAsync(cursor, 0, (size_t)NN * 4, stream);
  hipMemsetAsync(pooled, 0, (size_t)NG * 384 * 4, stream);

  k_hist   <<<(NE + 255) / 256, 256, 0, stream>>>(e_dst, counts);
  k_scan1  <<<SCAN_B, 256, 0, stream>>>(counts, bsum);
  k_scan2  <<<1, 256, 0, stream>>>(bsum, boff, offs);
  k_scan3  <<<SCAN_B, 256, 0, stream>>>(counts, boff, offs);
  k_scatter<<<(NE + 255) / 256, 256, 0, stream>>>(e_src, e_dst, offs, cursor, esrc);
  k_cvt    <<<1025, 256, 0, stream>>>(x, (unsigned long long*)xb, batch, gstart);

  WPtrs ws;
  ws.w[0] = lW1[0]; ws.w[1] = lW2[0];
  ws.w[2] = lW1[1]; ws.w[3] = lW2[1];
  ws.w[4] = lW1[2]; ws.w[5] = lW2[2];
  k_prep6<<<dim3(64, 6), 256, 0, stream>>>(ws, wb);
  auto plane = [&](int widx, int hilo) { return wb + (size_t)(widx * 2 + hilo) * 16384; };

  short* Hbuf[2] = {Hb0, Hb1};
  const int mlp_grid = (NN + 255) / 256;   // 196 persistent 2-tile blocks
  for (int l = 0; l < 3; ++l) {
    if (l == 0)
      k_aggregate<false><<<NN / 4, 256, 0, stream>>>((const unsigned*)xb, offs, esrc,
                                                     nullptr, nullptr, nullptr, nullptr,
                                                     st(0), (unsigned*)AGGh, (unsigned*)AGGl);
    else
      k_aggregate<true><<<NN / 4, 256, 0, stream>>>((const unsigned*)Hbuf[(l - 1) & 1], offs, esrc,
                                                    st(l - 1), st(l - 1) + 128, lg[l - 1], lbeta[l - 1],
                                                    st(l), (unsigned*)AGGh, (unsigned*)AGGl);
    k_mlp2<<<mlp_grid, 512, 0, stream>>>(AGGh, AGGl,
                                         plane(2 * l, 0), plane(2 * l, 1),
                                         plane(2 * l + 1, 0), plane(2 * l + 1, 1),
                                         lb1[l], lb2[l], Hbuf[l & 1], st(l));
    k_pool <<<dim3(8, NG), 256, 0, stream>>>((const unsigned short*)Hbuf[l & 1],
                                             st(l), st(l) + 128, lg[l], lbeta[l],
                                             gstart, pooled, l * 128);
  }

  k_fc1 <<<NG, 128, 0, stream>>>(pooled, gstart, pW1, pb1, z1);
  k_head<<<1, 128, 0, stream>>>(z1, pg, pbeta, pW2, pb2, out);
}